// Round 5
// baseline (1381.409 us; speedup 1.0000x reference)
//
#include <hip/hip_runtime.h>

#define HW 128
#define COUTC 512
#define NB 4097
#define NSEL 300
#define T_TOP 16384
#define TW 256          // words per mask row = T_TOP/64

typedef _Float16 half8 __attribute__((ext_vector_type(8)));
typedef _Float16 half4v __attribute__((ext_vector_type(4)));
typedef float floatx4 __attribute__((ext_vector_type(4)));

// ================= fast-path ws layout (bytes) =================
#define NWS_A1H   ((size_t)0)            // 34,611,200  (dead after conv1 -> MSK)
#define NWS_A1L   ((size_t)34611200)     // (dead after conv1 -> CBOX/CAREA)
#define NWS_W1H   ((size_t)69222400)
#define NWS_W1L   ((size_t)78659584)
#define NWS_A2H   ((size_t)88096768)
#define NWS_A2L   ((size_t)105402368)
#define NWS_W2H   ((size_t)122707968)
#define NWS_W2L   ((size_t)127426560)
#define NWS_X2    ((size_t)132145152)
#define NWS_BOXES ((size_t)165699584)
#define NWS_KEYS  ((size_t)168058880)    // reused as sorted keys (sk2)
#define NWS_SKEYS ((size_t)169238528)    // WT lives here until heads done
#define NWS_HIST  ((size_t)170418176)
#define NWS_CUR   ((size_t)170434816)
#define NWS_CNT   ((size_t)170451456)
#define NWS_BASE  ((size_t)170451712)
#define NWS_TOTAL ((size_t)170468352)

// ================= fallback ws layout =================
#define WS_X1     ((size_t)0)
#define WS_X2     ((size_t)33554432)
#define WS_BOXES  ((size_t)67108864)
#define WS_KEYS   ((size_t)69468160)
#define WS_SKEYS  ((size_t)70647808)
#define WS_HIST   ((size_t)71827456)
#define WS_CUR    ((size_t)71844096)
#define WS_CNT    ((size_t)71860736)
#define WS_BASE   ((size_t)71860992)

__device__ __forceinline__ void glds16(const void* g, void* l) {
    __builtin_amdgcn_global_load_lds(
        (const __attribute__((address_space(1))) void*)g,
        (__attribute__((address_space(3))) void*)l, 16, 0, 0);
}

// Activation layout (per padded row pr): [chunk(CIN/32)][sub(4)][pc(130)][8ch]
// Weight layout (per tap): [chunk(CIN/32)][sub(4)][oc(512)][8ch]

// ---------------- feature convert ----------------
__global__ __launch_bounds__(256) void convert_feat_kernel(
    const float* __restrict__ feat, _Float16* __restrict__ ah, _Float16* __restrict__ al)
{
    int p  = blockIdx.x;
    int pr = p / 130, pc = p % 130;
    int c  = threadIdx.x * 4;
    half4v vh = (half4v)(_Float16)0.f, vl = (half4v)(_Float16)0.f;
    if (pr != 0 && pr != 129 && pc != 0 && pc != 129) {
        float4 v = *(const float4*)&feat[(size_t)(((pr - 1) * HW) + (pc - 1)) * 1024 + c];
        float f[4] = {v.x, v.y, v.z, v.w};
        #pragma unroll
        for (int i = 0; i < 4; ++i) {
            float x = fmaxf(f[i], 0.f);
            _Float16 hi = (_Float16)x;
            vh[i] = hi;
            vl[i] = (_Float16)(x - (float)hi);
        }
    }
    size_t o = (size_t)pr * 133120 + (size_t)(c >> 5) * 4160
             + (size_t)((c >> 3) & 3) * 1040 + (size_t)pc * 8 + (c & 7);
    *(half4v*)&ah[o] = vh;
    *(half4v*)&al[o] = vl;
}

// ---------------- weight convert ----------------
template<int CIN>
__global__ __launch_bounds__(256) void convert_w_kernel(
    const float* __restrict__ w, _Float16* __restrict__ wh, _Float16* __restrict__ wl)
{
    constexpr int NU = CIN / 8;
    int gid = blockIdx.x * 256 + threadIdx.x;
    int oc = gid & 511;
    int rest = gid >> 9;
    int u = rest & (NU - 1);
    int tap = rest / NU;
    if (tap >= 9) return;
    int k0 = u * 8;
    half8 vh, vl;
    #pragma unroll
    for (int j = 0; j < 8; ++j) {
        float v = w[((size_t)tap * CIN + k0 + j) * 512 + oc] * 64.f;
        _Float16 hi = (_Float16)v;
        vh[j] = hi;
        vl[j] = (_Float16)(v - (float)hi);
    }
    size_t o = (size_t)tap * CIN * 512 + (size_t)(k0 >> 5) * 16384
             + (size_t)((k0 >> 3) & 3) * 4096 + (size_t)oc * 8;
    *(half8*)(wh + o) = vh;
    *(half8*)(wl + o) = vl;
}

// ---------------- head-weight transpose: WT[48][512] ----------------
__global__ __launch_bounds__(256) void wtrans_kernel(
    const float* __restrict__ w_s, const float* __restrict__ w_b, float* __restrict__ wt)
{
    int o = blockIdx.x;                 // 0..47
    for (int k = threadIdx.x; k < 512; k += 256) {
        float v = 0.f;
        if (o < 9)       v = w_s[k * 9 + o];
        else if (o < 45) v = w_b[k * 36 + (o - 9)];
        wt[o * 512 + k] = v;
    }
}

// ---------------- zero pad ring ----------------
__global__ __launch_bounds__(256) void zero_pads_kernel(_Float16* ah, _Float16* al)
{
    int i = blockIdx.x;
    int pr, pc;
    if (i < 130)      { pr = 0;        pc = i; }
    else if (i < 260) { pr = 129;      pc = i - 130; }
    else if (i < 388) { pr = i - 259;  pc = 0; }
    else              { pr = i - 387;  pc = 129; }
    int t = threadIdx.x;
    if (t >= 128) return;
    _Float16* dst = (t & 64) ? al : ah;
    int u = t & 63;
    size_t o = (size_t)pr * 66560 + (size_t)(u >> 2) * 4160 + (size_t)(u & 3) * 1040 + (size_t)pc * 8;
    *(float4*)(dst + o) = make_float4(0.f, 0.f, 0.f, 0.f);
}

// ---------------- conv 3x3 fp16-split MFMA, BK=64 ----------------
template<int CIN, bool SPLIT_OUT>
__global__ __launch_bounds__(256) void conv_mfma_kernel(
    const _Float16* __restrict__ ah, const _Float16* __restrict__ al,
    const _Float16* __restrict__ wh, const _Float16* __restrict__ wl,
    const float* __restrict__ bias,
    _Float16* __restrict__ oh, _Float16* __restrict__ ol,
    float* __restrict__ of)
{
    constexpr int ROWSTR = CIN * 130;
    constexpr int TAPW   = CIN * 512;
    // 64KB: AHI [2][4096] @0, ALO @8192, BHI @16384, BLO @24576 (halves)
    __shared__ __align__(16) _Float16 lds[32768];

    int bx = blockIdx.x;
    int h  = bx & 127;
    int n0 = (bx >> 7) << 7;

    int tid  = threadIdx.x;
    int wave = tid >> 6;
    int lane = tid & 63;
    int fr = lane & 15;
    int fq = lane >> 4;

    int aoff0 = fq * 1040 + (32 * wave + fr) * 8;
    int aoff1 = aoff0 + 128;
    int boff0 = fq * 4096 + (n0 + 32 * wave + fr) * 8;
    int boff1 = boff0 + 128;

    int wm = wave & 1, wn = wave >> 1;

    floatx4 acc[4][4];
    #pragma unroll
    for (int i = 0; i < 4; ++i)
        #pragma unroll
        for (int j = 0; j < 4; ++j)
            acc[i][j] = (floatx4){0.f, 0.f, 0.f, 0.f};

    #pragma unroll
    for (int tap = 0; tap < 9; ++tap) {
        int dy = tap / 3 - 1, dx = tap % 3 - 1;
        const _Float16* gAh = ah + (size_t)(h + dy + 1) * ROWSTR + (dx + 1) * 8;
        const _Float16* gAl = al + (size_t)(h + dy + 1) * ROWSTR + (dx + 1) * 8;
        const _Float16* gBh = wh + (size_t)tap * TAPW;
        const _Float16* gBl = wl + (size_t)tap * TAPW;

        for (int kc = 0; kc < CIN; kc += 64) {
            #pragma unroll
            for (int s = 0; s < 2; ++s) {
                int ab = ((kc >> 5) + s) * 4160;
                int bb = ((kc >> 5) + s) * 16384;
                _Float16* A0 = lds +          s * 4096 + 2 * wave * 512;
                _Float16* L0 = lds + 8192  +  s * 4096 + 2 * wave * 512;
                _Float16* B0 = lds + 16384 +  s * 4096 + 2 * wave * 512;
                _Float16* C0 = lds + 24576 +  s * 4096 + 2 * wave * 512;
                glds16(gAh + ab + aoff0, A0);
                glds16(gAh + ab + aoff1, A0 + 512);
                glds16(gAl + ab + aoff0, L0);
                glds16(gAl + ab + aoff1, L0 + 512);
                glds16(gBh + bb + boff0, B0);
                glds16(gBh + bb + boff1, B0 + 512);
                glds16(gBl + bb + boff0, C0);
                glds16(gBl + bb + boff1, C0 + 512);
            }
            __syncthreads();

            #pragma unroll
            for (int s = 0; s < 2; ++s) {
                const _Float16* rAh = lds +          s * 4096 + wm * 2048 + fq * 128 + fr * 8;
                const _Float16* rAl = rAh + 8192;
                const _Float16* rBh = lds + 16384 +  s * 4096 + wn * 2048 + fq * 128 + fr * 8;
                const _Float16* rBl = rBh + 8192;

                half8 fah[4], fal[4], fbh[4], fbl[4];
                #pragma unroll
                for (int i = 0; i < 4; ++i) {
                    fah[i] = *(const half8*)(rAh + i * 512);
                    fal[i] = *(const half8*)(rAl + i * 512);
                    fbh[i] = *(const half8*)(rBh + i * 512);
                    fbl[i] = *(const half8*)(rBl + i * 512);
                }
                #pragma unroll
                for (int i = 0; i < 4; ++i)
                    #pragma unroll
                    for (int j = 0; j < 4; ++j)
                        acc[i][j] = __builtin_amdgcn_mfma_f32_16x16x32_f16(fah[i], fbh[j], acc[i][j], 0, 0, 0);
                #pragma unroll
                for (int i = 0; i < 4; ++i)
                    #pragma unroll
                    for (int j = 0; j < 4; ++j)
                        acc[i][j] = __builtin_amdgcn_mfma_f32_16x16x32_f16(fah[i], fbl[j], acc[i][j], 0, 0, 0);
                #pragma unroll
                for (int i = 0; i < 4; ++i)
                    #pragma unroll
                    for (int j = 0; j < 4; ++j)
                        acc[i][j] = __builtin_amdgcn_mfma_f32_16x16x32_f16(fal[i], fbh[j], acc[i][j], 0, 0, 0);
            }
            __syncthreads();
        }
    }

    const float scale = 1.f / 64.f;
    int em = 64 * wm + fq * 4;
    int en = 64 * wn + fr;
    #pragma unroll
    for (int j = 0; j < 4; ++j) {
        int oc = n0 + en + 16 * j;
        float b = bias[oc];
        #pragma unroll
        for (int i = 0; i < 4; ++i) {
            #pragma unroll
            for (int r = 0; r < 4; ++r) {
                int w = em + 16 * i + r;
                float v = fmaf(acc[i][j][r], scale, b);
                if (SPLIT_OUT) {
                    v = fmaxf(v, 0.f);
                    _Float16 hi = (_Float16)v;
                    size_t o = (size_t)(h + 1) * 66560 + (size_t)(oc >> 5) * 4160
                             + (size_t)((oc >> 3) & 3) * 1040 + (size_t)(w + 1) * 8 + (oc & 7);
                    oh[o] = hi;
                    ol[o] = (_Float16)(v - (float)hi);
                } else {
                    of[((size_t)h * HW + w) * COUTC + oc] = v;
                }
            }
        }
    }
}

// ---------------- fallback fp32 conv ----------------
template<int CIN, bool RELU_IN, bool RELU_OUT>
__global__ __launch_bounds__(256) void conv3x3_kernel(
    const float* __restrict__ in, const float* __restrict__ wgt,
    const float* __restrict__ bias, float* __restrict__ out)
{
    __shared__ float As[32][68];
    __shared__ float Bs[32][64];
    int bx = blockIdx.x;
    int mtile = bx & 255, ntile = bx >> 8;
    int h = mtile >> 1, w0 = (mtile & 1) << 6, n0 = ntile << 6;
    int tid = threadIdx.x, ty = tid >> 4, tx = tid & 15;
    float acc[4][4] = {{0.f}};
    const int KTOT = 9 * CIN;
    for (int k0 = 0; k0 < KTOT; k0 += 32) {
        int tap = k0 / CIN, icb = k0 % CIN;
        int dy = tap / 3 - 1, dx = tap % 3 - 1;
        int row = h + dy;
        bool rowok = ((unsigned)row < HW);
        {
            int pix = tid >> 3, cs = (tid & 7) << 2;
            #pragma unroll
            for (int p = 0; p < 2; ++p) {
                int px = pix + p * 32;
                int wcol = w0 + px + dx;
                float4 v = make_float4(0.f, 0.f, 0.f, 0.f);
                if (rowok && (unsigned)wcol < HW) {
                    v = *(const float4*)&in[((size_t)row * HW + wcol) * CIN + icb + cs];
                    if (RELU_IN) {
                        v.x = fmaxf(v.x, 0.f); v.y = fmaxf(v.y, 0.f);
                        v.z = fmaxf(v.z, 0.f); v.w = fmaxf(v.w, 0.f);
                    }
                }
                As[cs + 0][px] = v.x; As[cs + 1][px] = v.y;
                As[cs + 2][px] = v.z; As[cs + 3][px] = v.w;
            }
        }
        {
            int kr = tid >> 4, nc = (tid & 15) << 2;
            #pragma unroll
            for (int p = 0; p < 2; ++p) {
                int k = kr + p * 16;
                *(float4*)&Bs[k][nc] = *(const float4*)&wgt[(size_t)(k0 + k) * COUTC + n0 + nc];
            }
        }
        __syncthreads();
        #pragma unroll
        for (int kk = 0; kk < 32; ++kk) {
            float4 a = *(const float4*)&As[kk][ty << 2];
            float4 b = *(const float4*)&Bs[kk][tx << 2];
            float av[4] = {a.x, a.y, a.z, a.w};
            float bv[4] = {b.x, b.y, b.z, b.w};
            #pragma unroll
            for (int i = 0; i < 4; ++i)
                #pragma unroll
                for (int j = 0; j < 4; ++j)
                    acc[i][j] = fmaf(av[i], bv[j], acc[i][j]);
        }
        __syncthreads();
    }
    float4 bi = *(const float4*)&bias[n0 + (tx << 2)];
    float bv2[4] = {bi.x, bi.y, bi.z, bi.w};
    #pragma unroll
    for (int i = 0; i < 4; ++i) {
        float4 o;
        o.x = acc[i][0] + bv2[0]; o.y = acc[i][1] + bv2[1];
        o.z = acc[i][2] + bv2[2]; o.w = acc[i][3] + bv2[3];
        if (RELU_OUT) {
            o.x = fmaxf(o.x, 0.f); o.y = fmaxf(o.y, 0.f);
            o.z = fmaxf(o.z, 0.f); o.w = fmaxf(o.w, 0.f);
        }
        *(float4*)&out[((size_t)(h * HW) + w0 + (ty << 2) + i) * COUTC + n0 + (tx << 2)] = o;
    }
}

// ---------------- heads + sigmoid + decode + candidate filter ----------------
__global__ __launch_bounds__(256) void heads_decode_kernel(
    const float* __restrict__ x, const float* __restrict__ wt,
    const float* __restrict__ b_s, const float* __restrict__ b_b,
    float4* __restrict__ boxes, unsigned long long* __restrict__ keys,
    int* __restrict__ cnt, int* __restrict__ hist)
{
    __shared__ float xs[4][512];
    __shared__ float outs[4][45];
    int wave = threadIdx.x >> 6;
    int lane = threadIdx.x & 63;
    int pix  = blockIdx.x * 4 + wave;

    const float4* xp = (const float4*)&x[(size_t)pix * COUTC];
    *(float4*)&xs[wave][lane * 4]       = xp[lane];
    *(float4*)&xs[wave][256 + lane * 4] = xp[64 + lane];
    __syncthreads();

    if (lane < 45) {
        float acc = (lane < 9) ? b_s[lane] : b_b[lane - 9];
        const float4* wrow = (const float4*)(wt + lane * 512);
        const float4* xrow = (const float4*)xs[wave];
        #pragma unroll 4
        for (int k = 0; k < 128; ++k) {
            float4 w = wrow[k], xv = xrow[k];
            acc = fmaf(xv.x, w.x, acc);
            acc = fmaf(xv.y, w.y, acc);
            acc = fmaf(xv.z, w.z, acc);
            acc = fmaf(xv.w, w.w, acc);
        }
        outs[wave][lane] = acc;
    }
    __syncthreads();

    if (lane < 9) {
        int h = pix >> 7, w = pix & 127;
        int a = lane;
        float z   = outs[wave][a];
        float dyv = outs[wave][9 + 4 * a + 0];
        float dxv = outs[wave][9 + 4 * a + 1];
        float dhv = outs[wave][9 + 4 * a + 2];
        float dwv = outs[wave][9 + 4 * a + 3];
        float sc  = (a < 3) ? 128.f : ((a < 6) ? 256.f : 512.f);
        int r = a - (a / 3) * 3;
        float ratio = (r == 0) ? 0.5f : ((r == 1) ? 1.f : 2.f);
        float sr = sqrtf(ratio);
        float ahh = sc * sr, aww = sc / sr;
        float acy = ((float)h + 0.5f) * 16.f;
        float acx = ((float)w + 0.5f) * 16.f;
        float cy = fmaf(dyv, ahh, acy);
        float cx = fmaf(dxv, aww, acx);
        float hh = ahh * expf(dhv);
        float ww = aww * expf(dwv);
        float y1 = fminf(fmaxf(cy - 0.5f * hh, 0.f), 2048.f);
        float x1 = fminf(fmaxf(cx - 0.5f * ww, 0.f), 2048.f);
        float y2 = fminf(fmaxf(cy + 0.5f * hh, 0.f), 2048.f);
        float x2 = fminf(fmaxf(cx + 0.5f * ww, 0.f), 2048.f);
        int gi = pix * 9 + a;
        boxes[gi] = make_float4(y1, x1, y2, x2);
        float s = 1.f / (1.f + expf(-z));
        if (s >= 0.5f) {
            unsigned u = __float_as_uint(s);
            unsigned d = 0x3F800000u - u;
            unsigned long long key = ((unsigned long long)d << 18) | (unsigned)gi;
            int p = atomicAdd(cnt, 1);
            keys[p] = key;
            atomicAdd(&hist[d >> 11], 1);
        }
    }
}

__global__ __launch_bounds__(256) void scan_kernel(
    const int* __restrict__ hist, int* __restrict__ base)
{
    __shared__ int buf[256];
    __shared__ int carry;
    int tid = threadIdx.x;
    if (tid == 0) carry = 0;
    __syncthreads();
    for (int c = 0; c < NB; c += 256) {
        int idx = c + tid;
        int v = (idx < NB) ? hist[idx] : 0;
        buf[tid] = v;
        __syncthreads();
        for (int s = 1; s < 256; s <<= 1) {
            int t = (tid >= s) ? buf[tid - s] : 0;
            __syncthreads();
            buf[tid] += t;
            __syncthreads();
        }
        if (idx < NB) base[idx] = carry + buf[tid] - v;
        __syncthreads();
        if (tid == 0) carry += buf[255];
        __syncthreads();
    }
    if (tid == 0) base[NB] = carry;
}

__global__ __launch_bounds__(256) void scatter_kernel(
    const unsigned long long* __restrict__ keys, const int* __restrict__ cnt,
    const int* __restrict__ base, int* __restrict__ cur,
    unsigned long long* __restrict__ skeys)
{
    int i = blockIdx.x * 256 + threadIdx.x;
    if (i < *cnt) {
        unsigned long long k = keys[i];
        int b = (int)(k >> 29);
        int p = base[b] + atomicAdd(&cur[b], 1);
        skeys[p] = k;
    }
}

// ---------------- per-bucket rank sort ----------------
__global__ __launch_bounds__(64) void sortb_kernel(
    const unsigned long long* __restrict__ skeys, const int* __restrict__ base,
    unsigned long long* __restrict__ sk2)
{
    __shared__ unsigned long long sk[2048];
    int b = blockIdx.x;
    int s0 = base[b];
    int n = base[b + 1] - s0;
    if (n <= 0) return;
    int lane = threadIdx.x;
    if (n <= 2048) {
        for (int i = lane; i < n; i += 64) sk[i] = skeys[s0 + i];
        for (int i = lane; i < n; i += 64) {
            unsigned long long k = sk[i];
            int r = 0;
            for (int j = 0; j < n; ++j) r += (sk[j] < k) ? 1 : 0;
            sk2[s0 + r] = k;
        }
    } else {
        const unsigned long long* src = skeys + s0;
        for (int i = lane; i < n; i += 64) {
            unsigned long long k = src[i];
            int r = 0;
            for (int j = 0; j < n; ++j) r += (src[j] < k) ? 1 : 0;
            sk2[s0 + r] = k;
        }
    }
}

// ---------------- gather top-T boxes/areas ----------------
__global__ __launch_bounds__(256) void gather_kernel(
    const unsigned long long* __restrict__ sk2, const int* __restrict__ cnt,
    const float4* __restrict__ boxes, float4* __restrict__ cboxes, float* __restrict__ careas)
{
    int i = blockIdx.x * 256 + threadIdx.x;
    int Tc = min(*cnt, T_TOP);
    if (i < Tc) {
        unsigned long long k = sk2[i];
        float4 b = boxes[k & 0x3FFFFull];
        cboxes[i] = b;
        careas[i] = (b.z - b.x) * (b.w - b.y);
    }
}

// ---------------- pairwise suppression bitmask ----------------
__global__ __launch_bounds__(256) void mask_kernel(
    const float4* __restrict__ cboxes, const float* __restrict__ careas,
    unsigned long long* __restrict__ msk)
{
    int bi = blockIdx.y, bj = blockIdx.x;
    if (bj < bi) return;
    __shared__ float4 jb[256];
    __shared__ float  ja[256];
    int t = threadIdx.x;
    int j0 = bj << 8;
    jb[t] = cboxes[j0 + t];
    ja[t] = careas[j0 + t];
    __syncthreads();
    int i = (bi << 8) + t;
    float4 ci = cboxes[i];
    float ca = careas[i];
    unsigned long long word = 0;
    for (int jj = 0; jj < 256; ++jj) {
        int j = j0 + jj;
        float4 b = jb[jj];
        float iy = fmaxf(0.f, fminf(ci.z, b.z) - fmaxf(ci.x, b.x));
        float ix = fmaxf(0.f, fminf(ci.w, b.w) - fmaxf(ci.y, b.y));
        float inter = iy * ix;
        float iou = inter / (ca + ja[jj] - inter + 1e-9f);
        bool bit = (j == i) || (j > i && iou > 0.7f);
        if (bit) word |= 1ull << (jj & 63);
        if ((jj & 63) == 63) {
            msk[(size_t)i * TW + (bj << 2) + (jj >> 6)] = word;
            word = 0;
        }
    }
}

// ---------------- greedy walk: 2-deep speculative row prefetch ----------------
__global__ __launch_bounds__(64) void walk_kernel(
    const unsigned long long* __restrict__ sk2, const int* __restrict__ cnt,
    const float4* __restrict__ cboxes, const float* __restrict__ careas,
    const unsigned long long* __restrict__ msk, const float4* __restrict__ boxes,
    float* __restrict__ out)
{
    __shared__ unsigned long long sup[TW];
    __shared__ float4 sbox[NSEL];
    __shared__ float  sarea[NSEL];
    int lane = threadIdx.x;
    for (int i = lane; i < 1800; i += 64) out[i] = 0.f;
    #pragma unroll
    for (int k = 0; k < 4; ++k) sup[lane * 4 + k] = 0ull;
    __syncthreads();

    int total = *cnt;
    int Tc = min(total, T_TOP);
    int sel = 0;

    auto scanFrom = [&](int p) -> int {
        if (p < 0 || p >= Tc) return -1;
        int w = p >> 6;
        unsigned long long f = (~sup[w]) & (~0ull << (p & 63));
        while (f == 0ull) {
            ++w;
            if (w >= TW) return -1;
            f = ~sup[w];
        }
        int c = (w << 6) + __builtin_ctzll(f);
        return (c < Tc) ? c : -1;
    };
    auto loadRow = [&](int i, unsigned long long* r) {
        const unsigned long long* row = msk + (size_t)i * TW;
        #pragma unroll
        for (int k = 0; k < 4; ++k) r[k] = row[lane * 4 + k];
    };

    unsigned long long r0[4], r1[4], r2n[4];
    int idx = scanFrom(0);
    if (idx >= 0) loadRow(idx, r0);
    int idx2 = (idx >= 0) ? scanFrom(idx + 1) : -1;   // speculative (pre-OR of r0)
    if (idx2 >= 0) loadRow(idx2, r1);

    while (idx >= 0 && sel < NSEL) {
        float4 cb = cboxes[idx];
        float ca = careas[idx];
        if (lane == 0) {
            unsigned long long key = sk2[idx];
            out[sel * 4 + 0] = cb.x; out[sel * 4 + 1] = cb.y;
            out[sel * 4 + 2] = cb.z; out[sel * 4 + 3] = cb.w;
            out[1200 + sel] = __uint_as_float(0x3F800000u - (unsigned)(key >> 18));
            out[1500 + sel] = 1.f;
            sbox[sel] = cb;
            sarea[sel] = ca;
        }
        sel++;
        if (sel >= NSEL) break;

        // speculate 2 ahead (before r0 is OR'd)
        int idx3 = (idx2 >= 0) ? scanFrom(idx2 + 1) : -1;
        if (idx3 >= 0) loadRow(idx3, r2n);

        // commit row of idx
        #pragma unroll
        for (int k = 0; k < 4; ++k) sup[lane * 4 + k] |= r0[k];
        __syncthreads();

        // verify idx2 against updated sup
        if (idx2 >= 0) {
            unsigned long long w = sup[idx2 >> 6];
            if ((w >> (idx2 & 63)) & 1ull) {        // mispredict (~0.3%)
                idx2 = scanFrom(idx2);
                if (idx2 >= 0) loadRow(idx2, r1);
                idx3 = (idx2 >= 0) ? scanFrom(idx2 + 1) : -1;
                if (idx3 >= 0) loadRow(idx3, r2n);
            }
        }
        idx = idx2;
        #pragma unroll
        for (int k = 0; k < 4; ++k) r0[k] = r1[k];
        idx2 = idx3;
        #pragma unroll
        for (int k = 0; k < 4; ++k) r1[k] = r2n[k];
    }

    // exact tail beyond T_TOP (expected never at current sizes)
    if (sel < NSEL && total > T_TOP) {
        for (int i = T_TOP; i < total && sel < NSEL; ++i) {
            unsigned long long key = sk2[i];
            float4 cb = boxes[key & 0x3FFFFull];
            float ca = (cb.z - cb.x) * (cb.w - cb.y);
            int supp = 0;
            for (int t = lane; t < sel; t += 64) {
                float4 s4 = sbox[t];
                float iy = fmaxf(0.f, fminf(s4.z, cb.z) - fmaxf(s4.x, cb.x));
                float ix = fmaxf(0.f, fminf(s4.w, cb.w) - fmaxf(s4.y, cb.y));
                float inter = iy * ix;
                float iou = inter / (sarea[t] + ca - inter + 1e-9f);
                if (iou > 0.7f) supp = 1;
            }
            if (__ballot(supp) == 0ull) {
                if (lane == 0) {
                    out[sel * 4 + 0] = cb.x; out[sel * 4 + 1] = cb.y;
                    out[sel * 4 + 2] = cb.z; out[sel * 4 + 3] = cb.w;
                    out[1200 + sel] = __uint_as_float(0x3F800000u - (unsigned)(key >> 18));
                    out[1500 + sel] = 1.f;
                    sbox[sel] = cb;
                    sarea[sel] = ca;
                }
                sel++;
            }
        }
    }
}

extern "C" void kernel_launch(void* const* d_in, const int* in_sizes, int n_in,
                              void* d_out, int out_size, void* d_ws, size_t ws_size,
                              hipStream_t stream) {
    const float* feat = (const float*)d_in[0];
    const float* w1   = (const float*)d_in[1];
    const float* b1   = (const float*)d_in[2];
    const float* w2   = (const float*)d_in[3];
    const float* b2   = (const float*)d_in[4];
    const float* w_s  = (const float*)d_in[5];
    const float* b_s  = (const float*)d_in[6];
    const float* w_b  = (const float*)d_in[7];
    const float* b_b  = (const float*)d_in[8];
    float* out = (float*)d_out;
    char* ws = (char*)d_ws;

    if (ws_size >= NWS_TOTAL) {
        _Float16* a1h = (_Float16*)(ws + NWS_A1H);
        _Float16* a1l = (_Float16*)(ws + NWS_A1L);
        _Float16* w1h = (_Float16*)(ws + NWS_W1H);
        _Float16* w1l = (_Float16*)(ws + NWS_W1L);
        _Float16* a2h = (_Float16*)(ws + NWS_A2H);
        _Float16* a2l = (_Float16*)(ws + NWS_A2L);
        _Float16* w2h = (_Float16*)(ws + NWS_W2H);
        _Float16* w2l = (_Float16*)(ws + NWS_W2L);
        float* x2 = (float*)(ws + NWS_X2);
        float4* boxes = (float4*)(ws + NWS_BOXES);
        unsigned long long* keys  = (unsigned long long*)(ws + NWS_KEYS);
        unsigned long long* skeys = (unsigned long long*)(ws + NWS_SKEYS);
        int* hist = (int*)(ws + NWS_HIST);
        int* cur  = (int*)(ws + NWS_CUR);
        int* cnt  = (int*)(ws + NWS_CNT);
        int* base = (int*)(ws + NWS_BASE);
        float* wt = (float*)(ws + NWS_SKEYS);    // WT[48][512]: dead before scatter writes skeys
        unsigned long long* msk = (unsigned long long*)(ws + NWS_A1H);
        float4* cbox  = (float4*)(ws + NWS_A1L);
        float*  carea = (float*)(ws + NWS_A1L + 262144);
        unsigned long long* sk2 = keys;

        hipMemsetAsync(ws + NWS_HIST, 0, (NWS_CNT - NWS_HIST) + 256, stream);
        convert_feat_kernel<<<16900, 256, 0, stream>>>(feat, a1h, a1l);
        convert_w_kernel<1024><<<2304, 256, 0, stream>>>(w1, w1h, w1l);
        convert_w_kernel< 512><<<1152, 256, 0, stream>>>(w2, w2h, w2l);
        wtrans_kernel<<<48, 256, 0, stream>>>(w_s, w_b, wt);
        zero_pads_kernel<<<516, 256, 0, stream>>>(a2h, a2l);
        conv_mfma_kernel<1024, true ><<<512, 256, 0, stream>>>(a1h, a1l, w1h, w1l, b1, a2h, a2l, nullptr);
        conv_mfma_kernel< 512, false><<<512, 256, 0, stream>>>(a2h, a2l, w2h, w2l, b2, nullptr, nullptr, x2);
        heads_decode_kernel<<<4096, 256, 0, stream>>>(x2, wt, b_s, b_b, boxes, keys, cnt, hist);
        scan_kernel<<<1, 256, 0, stream>>>(hist, base);
        scatter_kernel<<<576, 256, 0, stream>>>(keys, cnt, base, cur, skeys);
        sortb_kernel<<<NB, 64, 0, stream>>>(skeys, base, sk2);
        gather_kernel<<<64, 256, 0, stream>>>(sk2, cnt, boxes, cbox, carea);
        mask_kernel<<<dim3(64, 64), 256, 0, stream>>>(cbox, carea, msk);
        walk_kernel<<<1, 64, 0, stream>>>(sk2, cnt, cbox, carea, msk, boxes, out);
    } else {
        float* x1 = (float*)(ws + WS_X1);
        float* x2 = (float*)(ws + WS_X2);
        float4* boxes = (float4*)(ws + WS_BOXES);
        unsigned long long* keys  = (unsigned long long*)(ws + WS_KEYS);
        unsigned long long* skeys = (unsigned long long*)(ws + WS_SKEYS);
        int* hist = (int*)(ws + WS_HIST);
        int* cur  = (int*)(ws + WS_CUR);
        int* cnt  = (int*)(ws + WS_CNT);
        int* base = (int*)(ws + WS_BASE);
        float* wt = (float*)(ws + WS_SKEYS);
        unsigned long long* msk = (unsigned long long*)(ws + WS_X1);
        float4* cbox  = (float4*)(ws + WS_X2);
        float*  carea = (float*)(ws + WS_X2 + 262144);
        unsigned long long* sk2 = keys;

        hipMemsetAsync(ws + WS_HIST, 0, (WS_CNT - WS_HIST) + 256, stream);
        wtrans_kernel<<<48, 256, 0, stream>>>(w_s, w_b, wt);
        conv3x3_kernel<1024, true,  true ><<<2048, 256, 0, stream>>>(feat, w1, b1, x1);
        conv3x3_kernel< 512, false, false><<<2048, 256, 0, stream>>>(x1,   w2, b2, x2);
        heads_decode_kernel<<<4096, 256, 0, stream>>>(x2, wt, b_s, b_b, boxes, keys, cnt, hist);
        scan_kernel<<<1, 256, 0, stream>>>(hist, base);
        scatter_kernel<<<576, 256, 0, stream>>>(keys, cnt, base, cur, skeys);
        sortb_kernel<<<NB, 64, 0, stream>>>(skeys, base, sk2);
        gather_kernel<<<64, 256, 0, stream>>>(sk2, cnt, boxes, cbox, carea);
        mask_kernel<<<dim3(64, 64), 256, 0, stream>>>(cbox, carea, msk);
        walk_kernel<<<1, 64, 0, stream>>>(sk2, cnt, cbox, carea, msk, boxes, out);
    }
}

// Round 6
// 1127.892 us; speedup vs baseline: 1.2248x; 1.2248x over previous
//
#include <hip/hip_runtime.h>

#define HW 128
#define COUTC 512
#define NB 4097
#define NSEL 300
#define T_TOP 16384
#define TW 256          // words per mask row = T_TOP/64

typedef _Float16 half8 __attribute__((ext_vector_type(8)));
typedef _Float16 half4v __attribute__((ext_vector_type(4)));
typedef float floatx4 __attribute__((ext_vector_type(4)));

// ================= fast-path ws layout (bytes) =================
#define NWS_A1H   ((size_t)0)            // 34,611,200  (dead after conv1 -> MSK)
#define NWS_A1L   ((size_t)34611200)     // (dead after conv1 -> CBOX/CAREA)
#define NWS_W1H   ((size_t)69222400)
#define NWS_W1L   ((size_t)78659584)
#define NWS_A2H   ((size_t)88096768)
#define NWS_A2L   ((size_t)105402368)
#define NWS_W2H   ((size_t)122707968)
#define NWS_W2L   ((size_t)127426560)
#define NWS_X2    ((size_t)132145152)    // xh (16,777,216) + xl (16,777,216)
#define NWS_BOXES ((size_t)165699584)
#define NWS_KEYS  ((size_t)168058880)    // reused as sorted keys (sk2)
#define NWS_SKEYS ((size_t)169238528)    // wbh/wbl live here until heads done
#define NWS_HIST  ((size_t)170418176)
#define NWS_CUR   ((size_t)170434816)
#define NWS_CNT   ((size_t)170451456)
#define NWS_BASE  ((size_t)170451712)
#define NWS_TOTAL ((size_t)170468352)

// ================= fallback ws layout =================
#define WS_X1     ((size_t)0)
#define WS_X2     ((size_t)33554432)
#define WS_BOXES  ((size_t)67108864)
#define WS_KEYS   ((size_t)69468160)
#define WS_SKEYS  ((size_t)70647808)
#define WS_HIST   ((size_t)71827456)
#define WS_CUR    ((size_t)71844096)
#define WS_CNT    ((size_t)71860736)
#define WS_BASE   ((size_t)71860992)

__device__ __forceinline__ void glds16(const void* g, void* l) {
    __builtin_amdgcn_global_load_lds(
        (const __attribute__((address_space(1))) void*)g,
        (__attribute__((address_space(3))) void*)l, 16, 0, 0);
}

// Activation layout (per padded row pr): [chunk(CIN/32)][sub(4)][pc(130)][8ch]
// Weight layout (per tap): [chunk(CIN/32)][sub(4)][oc(512)][8ch]
// conv2-output (heads input) layout (per row h): [chunk(16)][sub(4)][pix(128)][8ch], rowstride 65536 halves

// ---------------- feature convert ----------------
__global__ __launch_bounds__(256) void convert_feat_kernel(
    const float* __restrict__ feat, _Float16* __restrict__ ah, _Float16* __restrict__ al)
{
    int p  = blockIdx.x;
    int pr = p / 130, pc = p % 130;
    int c  = threadIdx.x * 4;
    half4v vh = (half4v)(_Float16)0.f, vl = (half4v)(_Float16)0.f;
    if (pr != 0 && pr != 129 && pc != 0 && pc != 129) {
        float4 v = *(const float4*)&feat[(size_t)(((pr - 1) * HW) + (pc - 1)) * 1024 + c];
        float f[4] = {v.x, v.y, v.z, v.w};
        #pragma unroll
        for (int i = 0; i < 4; ++i) {
            float x = fmaxf(f[i], 0.f);
            _Float16 hi = (_Float16)x;
            vh[i] = hi;
            vl[i] = (_Float16)(x - (float)hi);
        }
    }
    size_t o = (size_t)pr * 133120 + (size_t)(c >> 5) * 4160
             + (size_t)((c >> 3) & 3) * 1040 + (size_t)pc * 8 + (c & 7);
    *(half4v*)&ah[o] = vh;
    *(half4v*)&al[o] = vl;
}

// ---------------- conv weight convert ----------------
template<int CIN>
__global__ __launch_bounds__(256) void convert_w_kernel(
    const float* __restrict__ w, _Float16* __restrict__ wh, _Float16* __restrict__ wl)
{
    constexpr int NU = CIN / 8;
    int gid = blockIdx.x * 256 + threadIdx.x;
    int oc = gid & 511;
    int rest = gid >> 9;
    int u = rest & (NU - 1);
    int tap = rest / NU;
    if (tap >= 9) return;
    int k0 = u * 8;
    half8 vh, vl;
    #pragma unroll
    for (int j = 0; j < 8; ++j) {
        float v = w[((size_t)tap * CIN + k0 + j) * 512 + oc] * 64.f;
        _Float16 hi = (_Float16)v;
        vh[j] = hi;
        vl[j] = (_Float16)(v - (float)hi);
    }
    size_t o = (size_t)tap * CIN * 512 + (size_t)(k0 >> 5) * 16384
             + (size_t)((k0 >> 3) & 3) * 4096 + (size_t)oc * 8;
    *(half8*)(wh + o) = vh;
    *(half8*)(wl + o) = vl;
}

// ---------------- head-weight convert: [48->64 pad][512] x64 split, [chunk16][sub4][n64][8] ----------------
__global__ __launch_bounds__(256) void wbconv_kernel(
    const float* __restrict__ w_s, const float* __restrict__ w_b,
    _Float16* __restrict__ wbh, _Float16* __restrict__ wbl)
{
    int gid = blockIdx.x * 256 + threadIdx.x;    // 32768 total = 64n x 512k
    int n = gid & 63;
    int k = gid >> 6;
    float v = 0.f;
    if (n < 9)       v = w_s[k * 9 + n] * 64.f;
    else if (n < 45) v = w_b[k * 36 + (n - 9)] * 64.f;
    _Float16 hi = (_Float16)v;
    size_t o = (size_t)(k >> 5) * 2048 + (size_t)((k >> 3) & 3) * 512 + (size_t)n * 8 + (k & 7);
    wbh[o] = hi;
    wbl[o] = (_Float16)(v - (float)hi);
}

// ---------------- zero pad ring ----------------
__global__ __launch_bounds__(256) void zero_pads_kernel(_Float16* ah, _Float16* al)
{
    int i = blockIdx.x;
    int pr, pc;
    if (i < 130)      { pr = 0;        pc = i; }
    else if (i < 260) { pr = 129;      pc = i - 130; }
    else if (i < 388) { pr = i - 259;  pc = 0; }
    else              { pr = i - 387;  pc = 129; }
    int t = threadIdx.x;
    if (t >= 128) return;
    _Float16* dst = (t & 64) ? al : ah;
    int u = t & 63;
    size_t o = (size_t)pr * 66560 + (size_t)(u >> 2) * 4160 + (size_t)(u & 3) * 1040 + (size_t)pc * 8;
    *(float4*)(dst + o) = make_float4(0.f, 0.f, 0.f, 0.f);
}

// ---------------- conv 3x3 fp16-split MFMA, BK=64 ----------------
// PAD=true : relu + split, padded swizzled write (conv1 -> conv2 input)
// PAD=false: split no relu, unpadded swizzled write (conv2 -> heads input)
template<int CIN, bool PAD>
__global__ __launch_bounds__(256) void conv_mfma_kernel(
    const _Float16* __restrict__ ah, const _Float16* __restrict__ al,
    const _Float16* __restrict__ wh, const _Float16* __restrict__ wl,
    const float* __restrict__ bias,
    _Float16* __restrict__ oh, _Float16* __restrict__ ol)
{
    constexpr int ROWSTR = CIN * 130;
    constexpr int TAPW   = CIN * 512;
    __shared__ __align__(16) _Float16 lds[32768];

    int bx = blockIdx.x;
    int h  = bx & 127;
    int n0 = (bx >> 7) << 7;

    int tid  = threadIdx.x;
    int wave = tid >> 6;
    int lane = tid & 63;
    int fr = lane & 15;
    int fq = lane >> 4;

    int aoff0 = fq * 1040 + (32 * wave + fr) * 8;
    int aoff1 = aoff0 + 128;
    int boff0 = fq * 4096 + (n0 + 32 * wave + fr) * 8;
    int boff1 = boff0 + 128;

    int wm = wave & 1, wn = wave >> 1;

    floatx4 acc[4][4];
    #pragma unroll
    for (int i = 0; i < 4; ++i)
        #pragma unroll
        for (int j = 0; j < 4; ++j)
            acc[i][j] = (floatx4){0.f, 0.f, 0.f, 0.f};

    #pragma unroll
    for (int tap = 0; tap < 9; ++tap) {
        int dy = tap / 3 - 1, dx = tap % 3 - 1;
        const _Float16* gAh = ah + (size_t)(h + dy + 1) * ROWSTR + (dx + 1) * 8;
        const _Float16* gAl = al + (size_t)(h + dy + 1) * ROWSTR + (dx + 1) * 8;
        const _Float16* gBh = wh + (size_t)tap * TAPW;
        const _Float16* gBl = wl + (size_t)tap * TAPW;

        for (int kc = 0; kc < CIN; kc += 64) {
            #pragma unroll
            for (int s = 0; s < 2; ++s) {
                int ab = ((kc >> 5) + s) * 4160;
                int bb = ((kc >> 5) + s) * 16384;
                _Float16* A0 = lds +          s * 4096 + 2 * wave * 512;
                _Float16* L0 = lds + 8192  +  s * 4096 + 2 * wave * 512;
                _Float16* B0 = lds + 16384 +  s * 4096 + 2 * wave * 512;
                _Float16* C0 = lds + 24576 +  s * 4096 + 2 * wave * 512;
                glds16(gAh + ab + aoff0, A0);
                glds16(gAh + ab + aoff1, A0 + 512);
                glds16(gAl + ab + aoff0, L0);
                glds16(gAl + ab + aoff1, L0 + 512);
                glds16(gBh + bb + boff0, B0);
                glds16(gBh + bb + boff1, B0 + 512);
                glds16(gBl + bb + boff0, C0);
                glds16(gBl + bb + boff1, C0 + 512);
            }
            __syncthreads();

            #pragma unroll
            for (int s = 0; s < 2; ++s) {
                const _Float16* rAh = lds +          s * 4096 + wm * 2048 + fq * 128 + fr * 8;
                const _Float16* rAl = rAh + 8192;
                const _Float16* rBh = lds + 16384 +  s * 4096 + wn * 2048 + fq * 128 + fr * 8;
                const _Float16* rBl = rBh + 8192;

                half8 fah[4], fal[4], fbh[4], fbl[4];
                #pragma unroll
                for (int i = 0; i < 4; ++i) {
                    fah[i] = *(const half8*)(rAh + i * 512);
                    fal[i] = *(const half8*)(rAl + i * 512);
                    fbh[i] = *(const half8*)(rBh + i * 512);
                    fbl[i] = *(const half8*)(rBl + i * 512);
                }
                #pragma unroll
                for (int i = 0; i < 4; ++i)
                    #pragma unroll
                    for (int j = 0; j < 4; ++j)
                        acc[i][j] = __builtin_amdgcn_mfma_f32_16x16x32_f16(fah[i], fbh[j], acc[i][j], 0, 0, 0);
                #pragma unroll
                for (int i = 0; i < 4; ++i)
                    #pragma unroll
                    for (int j = 0; j < 4; ++j)
                        acc[i][j] = __builtin_amdgcn_mfma_f32_16x16x32_f16(fah[i], fbl[j], acc[i][j], 0, 0, 0);
                #pragma unroll
                for (int i = 0; i < 4; ++i)
                    #pragma unroll
                    for (int j = 0; j < 4; ++j)
                        acc[i][j] = __builtin_amdgcn_mfma_f32_16x16x32_f16(fal[i], fbh[j], acc[i][j], 0, 0, 0);
            }
            __syncthreads();
        }
    }

    const float scale = 1.f / 64.f;
    int em = 64 * wm + fq * 4;
    int en = 64 * wn + fr;
    #pragma unroll
    for (int j = 0; j < 4; ++j) {
        int oc = n0 + en + 16 * j;
        float b = bias[oc];
        #pragma unroll
        for (int i = 0; i < 4; ++i) {
            #pragma unroll
            for (int r = 0; r < 4; ++r) {
                int w = em + 16 * i + r;
                float v = fmaf(acc[i][j][r], scale, b);
                if (PAD) {
                    v = fmaxf(v, 0.f);
                    _Float16 hi = (_Float16)v;
                    size_t o = (size_t)(h + 1) * 66560 + (size_t)(oc >> 5) * 4160
                             + (size_t)((oc >> 3) & 3) * 1040 + (size_t)(w + 1) * 8 + (oc & 7);
                    oh[o] = hi;
                    ol[o] = (_Float16)(v - (float)hi);
                } else {
                    _Float16 hi = (_Float16)v;
                    size_t o = (size_t)h * 65536 + (size_t)(oc >> 5) * 4096
                             + (size_t)((oc >> 3) & 3) * 1024 + (size_t)w * 8 + (oc & 7);
                    oh[o] = hi;
                    ol[o] = (_Float16)(v - (float)hi);
                }
            }
        }
    }
}

// ---------------- decode helper ----------------
__device__ __forceinline__ void decode_emit(
    int gi, float z, float dyv, float dxv, float dhv, float dwv,
    float4* __restrict__ boxes, unsigned long long* __restrict__ keys,
    int* __restrict__ cnt, int* __restrict__ hist)
{
    int a = gi % 9;
    int pix = gi / 9;
    int h = pix >> 7, w = pix & 127;
    float sc  = (a < 3) ? 128.f : ((a < 6) ? 256.f : 512.f);
    int r = a - (a / 3) * 3;
    float ratio = (r == 0) ? 0.5f : ((r == 1) ? 1.f : 2.f);
    float sr = sqrtf(ratio);
    float ahh = sc * sr, aww = sc / sr;
    float acy = ((float)h + 0.5f) * 16.f;
    float acx = ((float)w + 0.5f) * 16.f;
    float cy = fmaf(dyv, ahh, acy);
    float cx = fmaf(dxv, aww, acx);
    float hh = ahh * expf(dhv);
    float ww = aww * expf(dwv);
    float y1 = fminf(fmaxf(cy - 0.5f * hh, 0.f), 2048.f);
    float x1 = fminf(fmaxf(cx - 0.5f * ww, 0.f), 2048.f);
    float y2 = fminf(fmaxf(cy + 0.5f * hh, 0.f), 2048.f);
    float x2 = fminf(fmaxf(cx + 0.5f * ww, 0.f), 2048.f);
    boxes[gi] = make_float4(y1, x1, y2, x2);
    float s = 1.f / (1.f + expf(-z));
    if (s >= 0.5f) {
        unsigned u = __float_as_uint(s);
        unsigned d = 0x3F800000u - u;
        unsigned long long key = ((unsigned long long)d << 18) | (unsigned)gi;
        int p = atomicAdd(cnt, 1);
        keys[p] = key;
        atomicAdd(&hist[d >> 11], 1);
    }
}

// ---------------- heads via MFMA: M=256 px, N=48(pad 64), K=512 + inline decode ----------------
__global__ __launch_bounds__(256) void heads_mfma_kernel(
    const _Float16* __restrict__ xh, const _Float16* __restrict__ xl,
    const _Float16* __restrict__ wbh, const _Float16* __restrict__ wbl,
    const float* __restrict__ b_s, const float* __restrict__ b_b,
    float4* __restrict__ boxes, unsigned long long* __restrict__ keys,
    int* __restrict__ cnt, int* __restrict__ hist)
{
    __shared__ __align__(16) char smem[49152];
    _Float16* sAh = (_Float16*)smem;             // 8192 halves: [rowsel2][sub4][pix128][8]
    _Float16* sAl = (_Float16*)(smem + 16384);
    _Float16* sBh = (_Float16*)(smem + 32768);   // 2048 halves: [sub4][n64][8]
    _Float16* sBl = (_Float16*)(smem + 40960);
    float* outs = (float*)smem;                  // overlay after K-loop: [256][48]
    __shared__ float sb[48];

    int tid  = threadIdx.x;
    int wave = tid >> 6;
    int lane = tid & 63;
    int fr = lane & 15;
    int fq = lane >> 4;
    if (tid < 48) sb[tid] = (tid < 9) ? b_s[tid] : ((tid < 45) ? b_b[tid - 9] : 0.f);

    int h0 = blockIdx.x << 1;
    int rowsel = wave >> 1;
    int seg = (wave & 1) * 2048;                 // halves within row-chunk

    floatx4 acc[4][3];
    #pragma unroll
    for (int i = 0; i < 4; ++i)
        #pragma unroll
        for (int j = 0; j < 3; ++j)
            acc[i][j] = (floatx4){0.f, 0.f, 0.f, 0.f};

    for (int kc = 0; kc < 16; ++kc) {
        const _Float16* gxh = xh + (size_t)(h0 + rowsel) * 65536 + kc * 4096 + seg;
        const _Float16* gxl = xl + (size_t)(h0 + rowsel) * 65536 + kc * 4096 + seg;
        _Float16* dAh = sAh + rowsel * 4096 + seg;
        _Float16* dAl = sAl + rowsel * 4096 + seg;
        #pragma unroll
        for (int q = 0; q < 4; ++q) {
            glds16(gxh + q * 512 + lane * 8, dAh + q * 512);
            glds16(gxl + q * 512 + lane * 8, dAl + q * 512);
        }
        glds16(wbh + kc * 2048 + wave * 512 + lane * 8, sBh + wave * 512);
        glds16(wbl + kc * 2048 + wave * 512 + lane * 8, sBl + wave * 512);
        __syncthreads();

        half8 fah[4], fal[4], fbh[3], fbl[3];
        #pragma unroll
        for (int i = 0; i < 4; ++i) {
            int pixLocal = wave * 64 + 16 * i + fr;
            int aaddr = (pixLocal >> 7) * 4096 + fq * 1024 + (pixLocal & 127) * 8;
            fah[i] = *(const half8*)(sAh + aaddr);
            fal[i] = *(const half8*)(sAl + aaddr);
        }
        #pragma unroll
        for (int j = 0; j < 3; ++j) {
            int baddr = fq * 512 + (16 * j + fr) * 8;
            fbh[j] = *(const half8*)(sBh + baddr);
            fbl[j] = *(const half8*)(sBl + baddr);
        }
        #pragma unroll
        for (int i = 0; i < 4; ++i)
            #pragma unroll
            for (int j = 0; j < 3; ++j) {
                acc[i][j] = __builtin_amdgcn_mfma_f32_16x16x32_f16(fah[i], fbh[j], acc[i][j], 0, 0, 0);
                acc[i][j] = __builtin_amdgcn_mfma_f32_16x16x32_f16(fah[i], fbl[j], acc[i][j], 0, 0, 0);
                acc[i][j] = __builtin_amdgcn_mfma_f32_16x16x32_f16(fal[i], fbh[j], acc[i][j], 0, 0, 0);
            }
        __syncthreads();
    }

    const float scale = 1.f / 64.f;
    #pragma unroll
    for (int i = 0; i < 4; ++i)
        #pragma unroll
        for (int j = 0; j < 3; ++j)
            #pragma unroll
            for (int r = 0; r < 4; ++r) {
                int pixLocal = wave * 64 + 16 * i + fq * 4 + r;
                int n = 16 * j + fr;
                if (n < 48)
                    outs[pixLocal * 48 + n] = fmaf(acc[i][j][r], scale, sb[n]);
            }
    __syncthreads();

    int p = tid;
    #pragma unroll
    for (int a = 0; a < 9; ++a) {
        float z   = outs[p * 48 + a];
        float dyv = outs[p * 48 + 9 + 4 * a + 0];
        float dxv = outs[p * 48 + 9 + 4 * a + 1];
        float dhv = outs[p * 48 + 9 + 4 * a + 2];
        float dwv = outs[p * 48 + 9 + 4 * a + 3];
        int gi = (h0 * 128 + p) * 9 + a;
        decode_emit(gi, z, dyv, dxv, dhv, dwv, boxes, keys, cnt, hist);
    }
}

// ---------------- fallback fp32 conv ----------------
template<int CIN, bool RELU_IN, bool RELU_OUT>
__global__ __launch_bounds__(256) void conv3x3_kernel(
    const float* __restrict__ in, const float* __restrict__ wgt,
    const float* __restrict__ bias, float* __restrict__ out)
{
    __shared__ float As[32][68];
    __shared__ float Bs[32][64];
    int bx = blockIdx.x;
    int mtile = bx & 255, ntile = bx >> 8;
    int h = mtile >> 1, w0 = (mtile & 1) << 6, n0 = ntile << 6;
    int tid = threadIdx.x, ty = tid >> 4, tx = tid & 15;
    float acc[4][4] = {{0.f}};
    const int KTOT = 9 * CIN;
    for (int k0 = 0; k0 < KTOT; k0 += 32) {
        int tap = k0 / CIN, icb = k0 % CIN;
        int dy = tap / 3 - 1, dx = tap % 3 - 1;
        int row = h + dy;
        bool rowok = ((unsigned)row < HW);
        {
            int pix = tid >> 3, cs = (tid & 7) << 2;
            #pragma unroll
            for (int p = 0; p < 2; ++p) {
                int px = pix + p * 32;
                int wcol = w0 + px + dx;
                float4 v = make_float4(0.f, 0.f, 0.f, 0.f);
                if (rowok && (unsigned)wcol < HW) {
                    v = *(const float4*)&in[((size_t)row * HW + wcol) * CIN + icb + cs];
                    if (RELU_IN) {
                        v.x = fmaxf(v.x, 0.f); v.y = fmaxf(v.y, 0.f);
                        v.z = fmaxf(v.z, 0.f); v.w = fmaxf(v.w, 0.f);
                    }
                }
                As[cs + 0][px] = v.x; As[cs + 1][px] = v.y;
                As[cs + 2][px] = v.z; As[cs + 3][px] = v.w;
            }
        }
        {
            int kr = tid >> 4, nc = (tid & 15) << 2;
            #pragma unroll
            for (int p = 0; p < 2; ++p) {
                int k = kr + p * 16;
                *(float4*)&Bs[k][nc] = *(const float4*)&wgt[(size_t)(k0 + k) * COUTC + n0 + nc];
            }
        }
        __syncthreads();
        #pragma unroll
        for (int kk = 0; kk < 32; ++kk) {
            float4 a = *(const float4*)&As[kk][ty << 2];
            float4 b = *(const float4*)&Bs[kk][tx << 2];
            float av[4] = {a.x, a.y, a.z, a.w};
            float bv[4] = {b.x, b.y, b.z, b.w};
            #pragma unroll
            for (int i = 0; i < 4; ++i)
                #pragma unroll
                for (int j = 0; j < 4; ++j)
                    acc[i][j] = fmaf(av[i], bv[j], acc[i][j]);
        }
        __syncthreads();
    }
    float4 bi = *(const float4*)&bias[n0 + (tx << 2)];
    float bv2[4] = {bi.x, bi.y, bi.z, bi.w};
    #pragma unroll
    for (int i = 0; i < 4; ++i) {
        float4 o;
        o.x = acc[i][0] + bv2[0]; o.y = acc[i][1] + bv2[1];
        o.z = acc[i][2] + bv2[2]; o.w = acc[i][3] + bv2[3];
        if (RELU_OUT) {
            o.x = fmaxf(o.x, 0.f); o.y = fmaxf(o.y, 0.f);
            o.z = fmaxf(o.z, 0.f); o.w = fmaxf(o.w, 0.f);
        }
        *(float4*)&out[((size_t)(h * HW) + w0 + (ty << 2) + i) * COUTC + n0 + (tx << 2)] = o;
    }
}

// ---------------- fallback heads (R3-style: lane-consecutive weight reads) ----------------
__global__ __launch_bounds__(256) void heads_decode_kernel(
    const float* __restrict__ x, const float* __restrict__ w_s, const float* __restrict__ b_s,
    const float* __restrict__ w_b, const float* __restrict__ b_b,
    float4* __restrict__ boxes, unsigned long long* __restrict__ keys,
    int* __restrict__ cnt, int* __restrict__ hist)
{
    __shared__ float xs[4][512];
    __shared__ float outs[4][45];
    int wave = threadIdx.x >> 6;
    int lane = threadIdx.x & 63;
    int pix  = blockIdx.x * 4 + wave;

    const float4* xp = (const float4*)&x[(size_t)pix * COUTC];
    *(float4*)&xs[wave][lane * 4]       = xp[lane];
    *(float4*)&xs[wave][256 + lane * 4] = xp[64 + lane];
    __syncthreads();

    if (lane < 45) {
        const float* wp; int stride; float acc;
        if (lane < 9) { wp = w_s + lane;       stride = 9;  acc = b_s[lane]; }
        else          { wp = w_b + (lane - 9); stride = 36; acc = b_b[lane - 9]; }
        const float* xrow = xs[wave];
        for (int k = 0; k < 512; k += 4) {
            acc = fmaf(xrow[k + 0], wp[(k + 0) * stride], acc);
            acc = fmaf(xrow[k + 1], wp[(k + 1) * stride], acc);
            acc = fmaf(xrow[k + 2], wp[(k + 2) * stride], acc);
            acc = fmaf(xrow[k + 3], wp[(k + 3) * stride], acc);
        }
        outs[wave][lane] = acc;
    }
    __syncthreads();

    if (lane < 9) {
        int a = lane;
        decode_emit(pix * 9 + a, outs[wave][a],
                    outs[wave][9 + 4 * a + 0], outs[wave][9 + 4 * a + 1],
                    outs[wave][9 + 4 * a + 2], outs[wave][9 + 4 * a + 3],
                    boxes, keys, cnt, hist);
    }
}

__global__ __launch_bounds__(256) void scan_kernel(
    const int* __restrict__ hist, int* __restrict__ base)
{
    __shared__ int buf[256];
    __shared__ int carry;
    int tid = threadIdx.x;
    if (tid == 0) carry = 0;
    __syncthreads();
    for (int c = 0; c < NB; c += 256) {
        int idx = c + tid;
        int v = (idx < NB) ? hist[idx] : 0;
        buf[tid] = v;
        __syncthreads();
        for (int s = 1; s < 256; s <<= 1) {
            int t = (tid >= s) ? buf[tid - s] : 0;
            __syncthreads();
            buf[tid] += t;
            __syncthreads();
        }
        if (idx < NB) base[idx] = carry + buf[tid] - v;
        __syncthreads();
        if (tid == 0) carry += buf[255];
        __syncthreads();
    }
    if (tid == 0) base[NB] = carry;
}

__global__ __launch_bounds__(256) void scatter_kernel(
    const unsigned long long* __restrict__ keys, const int* __restrict__ cnt,
    const int* __restrict__ base, int* __restrict__ cur,
    unsigned long long* __restrict__ skeys)
{
    int i = blockIdx.x * 256 + threadIdx.x;
    if (i < *cnt) {
        unsigned long long k = keys[i];
        int b = (int)(k >> 29);
        int p = base[b] + atomicAdd(&cur[b], 1);
        skeys[p] = k;
    }
}

// ---------------- per-bucket rank sort (256 threads) ----------------
__global__ __launch_bounds__(256) void sortb_kernel(
    const unsigned long long* __restrict__ skeys, const int* __restrict__ base,
    unsigned long long* __restrict__ sk2)
{
    __shared__ unsigned long long sk[2048];
    int b = blockIdx.x;
    int s0 = base[b];
    int n = base[b + 1] - s0;
    if (n <= 0) return;
    int t = threadIdx.x;
    if (n <= 2048) {
        for (int i = t; i < n; i += 256) sk[i] = skeys[s0 + i];
        __syncthreads();
        for (int i = t; i < n; i += 256) {
            unsigned long long k = sk[i];
            int r = 0;
            for (int j = 0; j < n; ++j) r += (sk[j] < k) ? 1 : 0;
            sk2[s0 + r] = k;
        }
    } else {
        const unsigned long long* src = skeys + s0;
        for (int i = t; i < n; i += 256) {
            unsigned long long k = src[i];
            int r = 0;
            for (int j = 0; j < n; ++j) r += (src[j] < k) ? 1 : 0;
            sk2[s0 + r] = k;
        }
    }
}

// ---------------- gather top-T boxes/areas ----------------
__global__ __launch_bounds__(256) void gather_kernel(
    const unsigned long long* __restrict__ sk2, const int* __restrict__ cnt,
    const float4* __restrict__ boxes, float4* __restrict__ cboxes, float* __restrict__ careas)
{
    int i = blockIdx.x * 256 + threadIdx.x;
    int Tc = min(*cnt, T_TOP);
    if (i < Tc) {
        unsigned long long k = sk2[i];
        float4 b = boxes[k & 0x3FFFFull];
        cboxes[i] = b;
        careas[i] = (b.z - b.x) * (b.w - b.y);
    }
}

// ---------------- pairwise suppression bitmask ----------------
__global__ __launch_bounds__(256) void mask_kernel(
    const float4* __restrict__ cboxes, const float* __restrict__ careas,
    unsigned long long* __restrict__ msk)
{
    int bi = blockIdx.y, bj = blockIdx.x;
    if (bj < bi) return;
    __shared__ float4 jb[256];
    __shared__ float  ja[256];
    int t = threadIdx.x;
    int j0 = bj << 8;
    jb[t] = cboxes[j0 + t];
    ja[t] = careas[j0 + t];
    __syncthreads();
    int i = (bi << 8) + t;
    float4 ci = cboxes[i];
    float ca = careas[i];
    unsigned long long word = 0;
    for (int jj = 0; jj < 256; ++jj) {
        int j = j0 + jj;
        float4 b = jb[jj];
        float iy = fmaxf(0.f, fminf(ci.z, b.z) - fmaxf(ci.x, b.x));
        float ix = fmaxf(0.f, fminf(ci.w, b.w) - fmaxf(ci.y, b.y));
        float inter = iy * ix;
        float iou = inter / (ca + ja[jj] - inter + 1e-9f);
        bool bit = (j == i) || (j > i && iou > 0.7f);
        if (bit) word |= 1ull << (jj & 63);
        if ((jj & 63) == 63) {
            msk[(size_t)i * TW + (bj << 2) + (jj >> 6)] = word;
            word = 0;
        }
    }
}

// ---------------- greedy walk: 2-deep speculative row prefetch ----------------
__global__ __launch_bounds__(64) void walk_kernel(
    const unsigned long long* __restrict__ sk2, const int* __restrict__ cnt,
    const float4* __restrict__ cboxes, const float* __restrict__ careas,
    const unsigned long long* __restrict__ msk, const float4* __restrict__ boxes,
    float* __restrict__ out)
{
    __shared__ unsigned long long sup[TW];
    __shared__ float4 sbox[NSEL];
    __shared__ float  sarea[NSEL];
    int lane = threadIdx.x;
    for (int i = lane; i < 1800; i += 64) out[i] = 0.f;
    #pragma unroll
    for (int k = 0; k < 4; ++k) sup[lane * 4 + k] = 0ull;
    __syncthreads();

    int total = *cnt;
    int Tc = min(total, T_TOP);
    int sel = 0;

    auto scanFrom = [&](int p) -> int {
        if (p < 0 || p >= Tc) return -1;
        int w = p >> 6;
        unsigned long long f = (~sup[w]) & (~0ull << (p & 63));
        while (f == 0ull) {
            ++w;
            if (w >= TW) return -1;
            f = ~sup[w];
        }
        int c = (w << 6) + __builtin_ctzll(f);
        return (c < Tc) ? c : -1;
    };
    auto loadRow = [&](int i, unsigned long long* r) {
        const unsigned long long* row = msk + (size_t)i * TW;
        #pragma unroll
        for (int k = 0; k < 4; ++k) r[k] = row[lane * 4 + k];
    };

    unsigned long long r0[4], r1[4], r2n[4];
    int idx = scanFrom(0);
    if (idx >= 0) loadRow(idx, r0);
    int idx2 = (idx >= 0) ? scanFrom(idx + 1) : -1;
    if (idx2 >= 0) loadRow(idx2, r1);

    while (idx >= 0 && sel < NSEL) {
        float4 cb = cboxes[idx];
        float ca = careas[idx];
        if (lane == 0) {
            unsigned long long key = sk2[idx];
            out[sel * 4 + 0] = cb.x; out[sel * 4 + 1] = cb.y;
            out[sel * 4 + 2] = cb.z; out[sel * 4 + 3] = cb.w;
            out[1200 + sel] = __uint_as_float(0x3F800000u - (unsigned)(key >> 18));
            out[1500 + sel] = 1.f;
            sbox[sel] = cb;
            sarea[sel] = ca;
        }
        sel++;
        if (sel >= NSEL) break;

        int idx3 = (idx2 >= 0) ? scanFrom(idx2 + 1) : -1;
        if (idx3 >= 0) loadRow(idx3, r2n);

        #pragma unroll
        for (int k = 0; k < 4; ++k) sup[lane * 4 + k] |= r0[k];
        __syncthreads();

        if (idx2 >= 0) {
            unsigned long long w = sup[idx2 >> 6];
            if ((w >> (idx2 & 63)) & 1ull) {
                idx2 = scanFrom(idx2);
                if (idx2 >= 0) loadRow(idx2, r1);
                idx3 = (idx2 >= 0) ? scanFrom(idx2 + 1) : -1;
                if (idx3 >= 0) loadRow(idx3, r2n);
            }
        }
        idx = idx2;
        #pragma unroll
        for (int k = 0; k < 4; ++k) r0[k] = r1[k];
        idx2 = idx3;
        #pragma unroll
        for (int k = 0; k < 4; ++k) r1[k] = r2n[k];
    }

    if (sel < NSEL && total > T_TOP) {
        for (int i = T_TOP; i < total && sel < NSEL; ++i) {
            unsigned long long key = sk2[i];
            float4 cb = boxes[key & 0x3FFFFull];
            float ca = (cb.z - cb.x) * (cb.w - cb.y);
            int supp = 0;
            for (int t = lane; t < sel; t += 64) {
                float4 s4 = sbox[t];
                float iy = fmaxf(0.f, fminf(s4.z, cb.z) - fmaxf(s4.x, cb.x));
                float ix = fmaxf(0.f, fminf(s4.w, cb.w) - fmaxf(s4.y, cb.y));
                float inter = iy * ix;
                float iou = inter / (sarea[t] + ca - inter + 1e-9f);
                if (iou > 0.7f) supp = 1;
            }
            if (__ballot(supp) == 0ull) {
                if (lane == 0) {
                    out[sel * 4 + 0] = cb.x; out[sel * 4 + 1] = cb.y;
                    out[sel * 4 + 2] = cb.z; out[sel * 4 + 3] = cb.w;
                    out[1200 + sel] = __uint_as_float(0x3F800000u - (unsigned)(key >> 18));
                    out[1500 + sel] = 1.f;
                    sbox[sel] = cb;
                    sarea[sel] = ca;
                }
                sel++;
            }
        }
    }
}

extern "C" void kernel_launch(void* const* d_in, const int* in_sizes, int n_in,
                              void* d_out, int out_size, void* d_ws, size_t ws_size,
                              hipStream_t stream) {
    const float* feat = (const float*)d_in[0];
    const float* w1   = (const float*)d_in[1];
    const float* b1   = (const float*)d_in[2];
    const float* w2   = (const float*)d_in[3];
    const float* b2   = (const float*)d_in[4];
    const float* w_s  = (const float*)d_in[5];
    const float* b_s  = (const float*)d_in[6];
    const float* w_b  = (const float*)d_in[7];
    const float* b_b  = (const float*)d_in[8];
    float* out = (float*)d_out;
    char* ws = (char*)d_ws;

    if (ws_size >= NWS_TOTAL) {
        _Float16* a1h = (_Float16*)(ws + NWS_A1H);
        _Float16* a1l = (_Float16*)(ws + NWS_A1L);
        _Float16* w1h = (_Float16*)(ws + NWS_W1H);
        _Float16* w1l = (_Float16*)(ws + NWS_W1L);
        _Float16* a2h = (_Float16*)(ws + NWS_A2H);
        _Float16* a2l = (_Float16*)(ws + NWS_A2L);
        _Float16* w2h = (_Float16*)(ws + NWS_W2H);
        _Float16* w2l = (_Float16*)(ws + NWS_W2L);
        _Float16* xh  = (_Float16*)(ws + NWS_X2);
        _Float16* xl  = (_Float16*)(ws + NWS_X2 + 16777216);
        float4* boxes = (float4*)(ws + NWS_BOXES);
        unsigned long long* keys  = (unsigned long long*)(ws + NWS_KEYS);
        unsigned long long* skeys = (unsigned long long*)(ws + NWS_SKEYS);
        int* hist = (int*)(ws + NWS_HIST);
        int* cur  = (int*)(ws + NWS_CUR);
        int* cnt  = (int*)(ws + NWS_CNT);
        int* base = (int*)(ws + NWS_BASE);
        _Float16* wbh = (_Float16*)(ws + NWS_SKEYS);           // dead before scatter writes skeys
        _Float16* wbl = (_Float16*)(ws + NWS_SKEYS + 65536);
        unsigned long long* msk = (unsigned long long*)(ws + NWS_A1H);
        float4* cbox  = (float4*)(ws + NWS_A1L);
        float*  carea = (float*)(ws + NWS_A1L + 262144);
        unsigned long long* sk2 = keys;

        hipMemsetAsync(ws + NWS_HIST, 0, (NWS_CNT - NWS_HIST) + 256, stream);
        convert_feat_kernel<<<16900, 256, 0, stream>>>(feat, a1h, a1l);
        convert_w_kernel<1024><<<2304, 256, 0, stream>>>(w1, w1h, w1l);
        convert_w_kernel< 512><<<1152, 256, 0, stream>>>(w2, w2h, w2l);
        wbconv_kernel<<<128, 256, 0, stream>>>(w_s, w_b, wbh, wbl);
        zero_pads_kernel<<<516, 256, 0, stream>>>(a2h, a2l);
        conv_mfma_kernel<1024, true ><<<512, 256, 0, stream>>>(a1h, a1l, w1h, w1l, b1, a2h, a2l);
        conv_mfma_kernel< 512, false><<<512, 256, 0, stream>>>(a2h, a2l, w2h, w2l, b2, xh, xl);
        heads_mfma_kernel<<<64, 256, 0, stream>>>(xh, xl, wbh, wbl, b_s, b_b, boxes, keys, cnt, hist);
        scan_kernel<<<1, 256, 0, stream>>>(hist, base);
        scatter_kernel<<<576, 256, 0, stream>>>(keys, cnt, base, cur, skeys);
        sortb_kernel<<<NB, 256, 0, stream>>>(skeys, base, sk2);
        gather_kernel<<<64, 256, 0, stream>>>(sk2, cnt, boxes, cbox, carea);
        mask_kernel<<<dim3(64, 64), 256, 0, stream>>>(cbox, carea, msk);
        walk_kernel<<<1, 64, 0, stream>>>(sk2, cnt, cbox, carea, msk, boxes, out);
    } else {
        float* x1 = (float*)(ws + WS_X1);
        float* x2 = (float*)(ws + WS_X2);
        float4* boxes = (float4*)(ws + WS_BOXES);
        unsigned long long* keys  = (unsigned long long*)(ws + WS_KEYS);
        unsigned long long* skeys = (unsigned long long*)(ws + WS_SKEYS);
        int* hist = (int*)(ws + WS_HIST);
        int* cur  = (int*)(ws + WS_CUR);
        int* cnt  = (int*)(ws + WS_CNT);
        int* base = (int*)(ws + WS_BASE);
        unsigned long long* msk = (unsigned long long*)(ws + WS_X1);
        float4* cbox  = (float4*)(ws + WS_X2);
        float*  carea = (float*)(ws + WS_X2 + 262144);
        unsigned long long* sk2 = keys;

        hipMemsetAsync(ws + WS_HIST, 0, (WS_CNT - WS_HIST) + 256, stream);
        conv3x3_kernel<1024, true,  true ><<<2048, 256, 0, stream>>>(feat, w1, b1, x1);
        conv3x3_kernel< 512, false, false><<<2048, 256, 0, stream>>>(x1,   w2, b2, x2);
        heads_decode_kernel<<<4096, 256, 0, stream>>>(x2, w_s, b_s, w_b, b_b, boxes, keys, cnt, hist);
        scan_kernel<<<1, 256, 0, stream>>>(hist, base);
        scatter_kernel<<<576, 256, 0, stream>>>(keys, cnt, base, cur, skeys);
        sortb_kernel<<<NB, 256, 0, stream>>>(skeys, base, sk2);
        gather_kernel<<<64, 256, 0, stream>>>(sk2, cnt, boxes, cbox, carea);
        mask_kernel<<<dim3(64, 64), 256, 0, stream>>>(cbox, carea, msk);
        walk_kernel<<<1, 64, 0, stream>>>(sk2, cnt, cbox, carea, msk, boxes, out);
    }
}

// Round 7
// 1014.590 us; speedup vs baseline: 1.3615x; 1.1117x over previous
//
#include <hip/hip_runtime.h>

#define HW 128
#define COUTC 512
#define NB 4097
#define NSEL 300
#define T_TOP 4096
#define TW 64           // words per mask row = T_TOP/64

typedef _Float16 half8 __attribute__((ext_vector_type(8)));
typedef _Float16 half4v __attribute__((ext_vector_type(4)));
typedef float floatx4 __attribute__((ext_vector_type(4)));

// ================= fast-path ws layout (bytes) =================
#define NWS_A1H   ((size_t)0)            // 34,611,200  (dead after conv1 -> MSK 2MB)
#define NWS_A1L   ((size_t)34611200)     // (dead after conv1 -> CBOX/CAREA)
#define NWS_W1H   ((size_t)69222400)
#define NWS_W1L   ((size_t)78659584)
#define NWS_A2H   ((size_t)88096768)
#define NWS_A2L   ((size_t)105402368)
#define NWS_W2H   ((size_t)122707968)
#define NWS_W2L   ((size_t)127426560)
#define NWS_X2    ((size_t)132145152)    // xh (16,777,216) + xl (16,777,216)
#define NWS_BOXES ((size_t)165699584)
#define NWS_KEYS  ((size_t)168058880)    // reused as sorted keys (sk2)
#define NWS_SKEYS ((size_t)169238528)    // wbh/wbl live here until heads done
#define NWS_HIST  ((size_t)170418176)
#define NWS_CUR   ((size_t)170434816)
#define NWS_CNT   ((size_t)170451456)
#define NWS_BASE  ((size_t)170451712)
#define NWS_TOTAL ((size_t)170468352)

// ================= fallback ws layout =================
#define WS_X1     ((size_t)0)
#define WS_X2     ((size_t)33554432)
#define WS_BOXES  ((size_t)67108864)
#define WS_KEYS   ((size_t)69468160)
#define WS_SKEYS  ((size_t)70647808)
#define WS_HIST   ((size_t)71827456)
#define WS_CUR    ((size_t)71844096)
#define WS_CNT    ((size_t)71860736)
#define WS_BASE   ((size_t)71860992)

__device__ __forceinline__ void glds16(const void* g, void* l) {
    __builtin_amdgcn_global_load_lds(
        (const __attribute__((address_space(1))) void*)g,
        (__attribute__((address_space(3))) void*)l, 16, 0, 0);
}

// Activation layout (per padded row pr): [chunk(CIN/32)][sub(4)][pc(130)][8ch]
// Weight layout (per tap): [chunk(CIN/32)][sub(4)][oc(512)][8ch]
// conv2-output (heads input) layout (per row h): [chunk(16)][sub(4)][pix(128)][8ch], rowstride 65536 halves

// ---------------- feature convert ----------------
__global__ __launch_bounds__(256) void convert_feat_kernel(
    const float* __restrict__ feat, _Float16* __restrict__ ah, _Float16* __restrict__ al)
{
    int p  = blockIdx.x;
    int pr = p / 130, pc = p % 130;
    int c  = threadIdx.x * 4;
    half4v vh = (half4v)(_Float16)0.f, vl = (half4v)(_Float16)0.f;
    if (pr != 0 && pr != 129 && pc != 0 && pc != 129) {
        float4 v = *(const float4*)&feat[(size_t)(((pr - 1) * HW) + (pc - 1)) * 1024 + c];
        float f[4] = {v.x, v.y, v.z, v.w};
        #pragma unroll
        for (int i = 0; i < 4; ++i) {
            float x = fmaxf(f[i], 0.f);
            _Float16 hi = (_Float16)x;
            vh[i] = hi;
            vl[i] = (_Float16)(x - (float)hi);
        }
    }
    size_t o = (size_t)pr * 133120 + (size_t)(c >> 5) * 4160
             + (size_t)((c >> 3) & 3) * 1040 + (size_t)pc * 8 + (c & 7);
    *(half4v*)&ah[o] = vh;
    *(half4v*)&al[o] = vl;
}

// ---------------- fused prep: conv weights + head weights + a2 pad ring ----------------
template<int CIN>
__device__ __forceinline__ void convert_w_body(
    int b, const float* __restrict__ w, _Float16* __restrict__ wh, _Float16* __restrict__ wl)
{
    constexpr int NU = CIN / 8;
    int gid = b * 256 + threadIdx.x;
    int oc = gid & 511;
    int rest = gid >> 9;
    int u = rest & (NU - 1);
    int tap = rest / NU;
    if (tap >= 9) return;
    int k0 = u * 8;
    half8 vh, vl;
    #pragma unroll
    for (int j = 0; j < 8; ++j) {
        float v = w[((size_t)tap * CIN + k0 + j) * 512 + oc] * 64.f;
        _Float16 hi = (_Float16)v;
        vh[j] = hi;
        vl[j] = (_Float16)(v - (float)hi);
    }
    size_t o = (size_t)tap * CIN * 512 + (size_t)(k0 >> 5) * 16384
             + (size_t)((k0 >> 3) & 3) * 4096 + (size_t)oc * 8;
    *(half8*)(wh + o) = vh;
    *(half8*)(wl + o) = vl;
}

__global__ __launch_bounds__(256) void prep_kernel(
    const float* __restrict__ w1, _Float16* __restrict__ w1h, _Float16* __restrict__ w1l,
    const float* __restrict__ w2, _Float16* __restrict__ w2h, _Float16* __restrict__ w2l,
    const float* __restrict__ w_s, const float* __restrict__ w_b,
    _Float16* __restrict__ wbh, _Float16* __restrict__ wbl,
    _Float16* __restrict__ a2h, _Float16* __restrict__ a2l)
{
    int b = blockIdx.x;
    if (b < 2304) { convert_w_body<1024>(b, w1, w1h, w1l); return; }
    if (b < 3456) { convert_w_body<512>(b - 2304, w2, w2h, w2l); return; }
    if (b < 3584) {
        // head weights: [48->64 pad][512] x64 split, layout [chunk16][sub4][n64][8]
        int gid = (b - 3456) * 256 + threadIdx.x;    // 32768 = 64n x 512k
        int n = gid & 63;
        int k = gid >> 6;
        float v = 0.f;
        if (n < 9)       v = w_s[k * 9 + n] * 64.f;
        else if (n < 45) v = w_b[k * 36 + (n - 9)] * 64.f;
        _Float16 hi = (_Float16)v;
        size_t o = (size_t)(k >> 5) * 2048 + (size_t)((k >> 3) & 3) * 512 + (size_t)n * 8 + (k & 7);
        wbh[o] = hi;
        wbl[o] = (_Float16)(v - (float)hi);
        return;
    }
    {   // a2 pad ring (516 blocks)
        int i = b - 3584;
        int pr, pc;
        if (i < 130)      { pr = 0;        pc = i; }
        else if (i < 260) { pr = 129;      pc = i - 130; }
        else if (i < 388) { pr = i - 259;  pc = 0; }
        else              { pr = i - 387;  pc = 129; }
        int t = threadIdx.x;
        if (t >= 128) return;
        _Float16* dst = (t & 64) ? a2l : a2h;
        int u = t & 63;
        size_t o = (size_t)pr * 66560 + (size_t)(u >> 2) * 4160 + (size_t)(u & 3) * 1040 + (size_t)pc * 8;
        *(float4*)(dst + o) = make_float4(0.f, 0.f, 0.f, 0.f);
    }
}

// ---------------- conv 3x3 fp16-split MFMA, BK=64 ----------------
template<int CIN, bool PAD>
__global__ __launch_bounds__(256) void conv_mfma_kernel(
    const _Float16* __restrict__ ah, const _Float16* __restrict__ al,
    const _Float16* __restrict__ wh, const _Float16* __restrict__ wl,
    const float* __restrict__ bias,
    _Float16* __restrict__ oh, _Float16* __restrict__ ol)
{
    constexpr int ROWSTR = CIN * 130;
    constexpr int TAPW   = CIN * 512;
    __shared__ __align__(16) _Float16 lds[32768];

    int bx = blockIdx.x;
    int h  = bx & 127;
    int n0 = (bx >> 7) << 7;

    int tid  = threadIdx.x;
    int wave = tid >> 6;
    int lane = tid & 63;
    int fr = lane & 15;
    int fq = lane >> 4;

    int aoff0 = fq * 1040 + (32 * wave + fr) * 8;
    int aoff1 = aoff0 + 128;
    int boff0 = fq * 4096 + (n0 + 32 * wave + fr) * 8;
    int boff1 = boff0 + 128;

    int wm = wave & 1, wn = wave >> 1;

    floatx4 acc[4][4];
    #pragma unroll
    for (int i = 0; i < 4; ++i)
        #pragma unroll
        for (int j = 0; j < 4; ++j)
            acc[i][j] = (floatx4){0.f, 0.f, 0.f, 0.f};

    #pragma unroll
    for (int tap = 0; tap < 9; ++tap) {
        int dy = tap / 3 - 1, dx = tap % 3 - 1;
        const _Float16* gAh = ah + (size_t)(h + dy + 1) * ROWSTR + (dx + 1) * 8;
        const _Float16* gAl = al + (size_t)(h + dy + 1) * ROWSTR + (dx + 1) * 8;
        const _Float16* gBh = wh + (size_t)tap * TAPW;
        const _Float16* gBl = wl + (size_t)tap * TAPW;

        for (int kc = 0; kc < CIN; kc += 64) {
            #pragma unroll
            for (int s = 0; s < 2; ++s) {
                int ab = ((kc >> 5) + s) * 4160;
                int bb = ((kc >> 5) + s) * 16384;
                _Float16* A0 = lds +          s * 4096 + 2 * wave * 512;
                _Float16* L0 = lds + 8192  +  s * 4096 + 2 * wave * 512;
                _Float16* B0 = lds + 16384 +  s * 4096 + 2 * wave * 512;
                _Float16* C0 = lds + 24576 +  s * 4096 + 2 * wave * 512;
                glds16(gAh + ab + aoff0, A0);
                glds16(gAh + ab + aoff1, A0 + 512);
                glds16(gAl + ab + aoff0, L0);
                glds16(gAl + ab + aoff1, L0 + 512);
                glds16(gBh + bb + boff0, B0);
                glds16(gBh + bb + boff1, B0 + 512);
                glds16(gBl + bb + boff0, C0);
                glds16(gBl + bb + boff1, C0 + 512);
            }
            __syncthreads();

            #pragma unroll
            for (int s = 0; s < 2; ++s) {
                const _Float16* rAh = lds +          s * 4096 + wm * 2048 + fq * 128 + fr * 8;
                const _Float16* rAl = rAh + 8192;
                const _Float16* rBh = lds + 16384 +  s * 4096 + wn * 2048 + fq * 128 + fr * 8;
                const _Float16* rBl = rBh + 8192;

                half8 fah[4], fal[4], fbh[4], fbl[4];
                #pragma unroll
                for (int i = 0; i < 4; ++i) {
                    fah[i] = *(const half8*)(rAh + i * 512);
                    fal[i] = *(const half8*)(rAl + i * 512);
                    fbh[i] = *(const half8*)(rBh + i * 512);
                    fbl[i] = *(const half8*)(rBl + i * 512);
                }
                #pragma unroll
                for (int i = 0; i < 4; ++i)
                    #pragma unroll
                    for (int j = 0; j < 4; ++j)
                        acc[i][j] = __builtin_amdgcn_mfma_f32_16x16x32_f16(fah[i], fbh[j], acc[i][j], 0, 0, 0);
                #pragma unroll
                for (int i = 0; i < 4; ++i)
                    #pragma unroll
                    for (int j = 0; j < 4; ++j)
                        acc[i][j] = __builtin_amdgcn_mfma_f32_16x16x32_f16(fah[i], fbl[j], acc[i][j], 0, 0, 0);
                #pragma unroll
                for (int i = 0; i < 4; ++i)
                    #pragma unroll
                    for (int j = 0; j < 4; ++j)
                        acc[i][j] = __builtin_amdgcn_mfma_f32_16x16x32_f16(fal[i], fbh[j], acc[i][j], 0, 0, 0);
            }
            __syncthreads();
        }
    }

    const float scale = 1.f / 64.f;
    int em = 64 * wm + fq * 4;
    int en = 64 * wn + fr;
    #pragma unroll
    for (int j = 0; j < 4; ++j) {
        int oc = n0 + en + 16 * j;
        float b = bias[oc];
        #pragma unroll
        for (int i = 0; i < 4; ++i) {
            #pragma unroll
            for (int r = 0; r < 4; ++r) {
                int w = em + 16 * i + r;
                float v = fmaf(acc[i][j][r], scale, b);
                if (PAD) {
                    v = fmaxf(v, 0.f);
                    _Float16 hi = (_Float16)v;
                    size_t o = (size_t)(h + 1) * 66560 + (size_t)(oc >> 5) * 4160
                             + (size_t)((oc >> 3) & 3) * 1040 + (size_t)(w + 1) * 8 + (oc & 7);
                    oh[o] = hi;
                    ol[o] = (_Float16)(v - (float)hi);
                } else {
                    _Float16 hi = (_Float16)v;
                    size_t o = (size_t)h * 65536 + (size_t)(oc >> 5) * 4096
                             + (size_t)((oc >> 3) & 3) * 1024 + (size_t)w * 8 + (oc & 7);
                    oh[o] = hi;
                    ol[o] = (_Float16)(v - (float)hi);
                }
            }
        }
    }
}

// ---------------- decode helper ----------------
__device__ __forceinline__ void decode_emit(
    int gi, float z, float dyv, float dxv, float dhv, float dwv,
    float4* __restrict__ boxes, unsigned long long* __restrict__ keys,
    int* __restrict__ cnt, int* __restrict__ hist)
{
    int a = gi % 9;
    int pix = gi / 9;
    int h = pix >> 7, w = pix & 127;
    float sc  = (a < 3) ? 128.f : ((a < 6) ? 256.f : 512.f);
    int r = a - (a / 3) * 3;
    float ratio = (r == 0) ? 0.5f : ((r == 1) ? 1.f : 2.f);
    float sr = sqrtf(ratio);
    float ahh = sc * sr, aww = sc / sr;
    float acy = ((float)h + 0.5f) * 16.f;
    float acx = ((float)w + 0.5f) * 16.f;
    float cy = fmaf(dyv, ahh, acy);
    float cx = fmaf(dxv, aww, acx);
    float hh = ahh * expf(dhv);
    float ww = aww * expf(dwv);
    float y1 = fminf(fmaxf(cy - 0.5f * hh, 0.f), 2048.f);
    float x1 = fminf(fmaxf(cx - 0.5f * ww, 0.f), 2048.f);
    float y2 = fminf(fmaxf(cy + 0.5f * hh, 0.f), 2048.f);
    float x2 = fminf(fmaxf(cx + 0.5f * ww, 0.f), 2048.f);
    boxes[gi] = make_float4(y1, x1, y2, x2);
    float s = 1.f / (1.f + expf(-z));
    if (s >= 0.5f) {
        unsigned u = __float_as_uint(s);
        unsigned d = 0x3F800000u - u;
        unsigned long long key = ((unsigned long long)d << 18) | (unsigned)gi;
        int p = atomicAdd(cnt, 1);
        keys[p] = key;
        atomicAdd(&hist[d >> 11], 1);
    }
}

// ---------------- heads via MFMA: M=256 px, N=48(pad 64), K=512 + inline decode ----------------
__global__ __launch_bounds__(256) void heads_mfma_kernel(
    const _Float16* __restrict__ xh, const _Float16* __restrict__ xl,
    const _Float16* __restrict__ wbh, const _Float16* __restrict__ wbl,
    const float* __restrict__ b_s, const float* __restrict__ b_b,
    float4* __restrict__ boxes, unsigned long long* __restrict__ keys,
    int* __restrict__ cnt, int* __restrict__ hist)
{
    __shared__ __align__(16) char smem[49152];
    _Float16* sAh = (_Float16*)smem;             // 8192 halves: [rowsel2][sub4][pix128][8]
    _Float16* sAl = (_Float16*)(smem + 16384);
    _Float16* sBh = (_Float16*)(smem + 32768);   // 2048 halves: [sub4][n64][8]
    _Float16* sBl = (_Float16*)(smem + 40960);
    float* outs = (float*)smem;                  // overlay after K-loop: [256][48]
    __shared__ float sb[48];

    int tid  = threadIdx.x;
    int wave = tid >> 6;
    int lane = tid & 63;
    int fr = lane & 15;
    int fq = lane >> 4;
    if (tid < 48) sb[tid] = (tid < 9) ? b_s[tid] : ((tid < 45) ? b_b[tid - 9] : 0.f);

    int h0 = blockIdx.x << 1;
    int rowsel = wave >> 1;
    int seg = (wave & 1) * 2048;

    floatx4 acc[4][3];
    #pragma unroll
    for (int i = 0; i < 4; ++i)
        #pragma unroll
        for (int j = 0; j < 3; ++j)
            acc[i][j] = (floatx4){0.f, 0.f, 0.f, 0.f};

    for (int kc = 0; kc < 16; ++kc) {
        const _Float16* gxh = xh + (size_t)(h0 + rowsel) * 65536 + kc * 4096 + seg;
        const _Float16* gxl = xl + (size_t)(h0 + rowsel) * 65536 + kc * 4096 + seg;
        _Float16* dAh = sAh + rowsel * 4096 + seg;
        _Float16* dAl = sAl + rowsel * 4096 + seg;
        #pragma unroll
        for (int q = 0; q < 4; ++q) {
            glds16(gxh + q * 512 + lane * 8, dAh + q * 512);
            glds16(gxl + q * 512 + lane * 8, dAl + q * 512);
        }
        glds16(wbh + kc * 2048 + wave * 512 + lane * 8, sBh + wave * 512);
        glds16(wbl + kc * 2048 + wave * 512 + lane * 8, sBl + wave * 512);
        __syncthreads();

        half8 fah[4], fal[4], fbh[3], fbl[3];
        #pragma unroll
        for (int i = 0; i < 4; ++i) {
            int pixLocal = wave * 64 + 16 * i + fr;
            int aaddr = (pixLocal >> 7) * 4096 + fq * 1024 + (pixLocal & 127) * 8;
            fah[i] = *(const half8*)(sAh + aaddr);
            fal[i] = *(const half8*)(sAl + aaddr);
        }
        #pragma unroll
        for (int j = 0; j < 3; ++j) {
            int baddr = fq * 512 + (16 * j + fr) * 8;
            fbh[j] = *(const half8*)(sBh + baddr);
            fbl[j] = *(const half8*)(sBl + baddr);
        }
        #pragma unroll
        for (int i = 0; i < 4; ++i)
            #pragma unroll
            for (int j = 0; j < 3; ++j) {
                acc[i][j] = __builtin_amdgcn_mfma_f32_16x16x32_f16(fah[i], fbh[j], acc[i][j], 0, 0, 0);
                acc[i][j] = __builtin_amdgcn_mfma_f32_16x16x32_f16(fah[i], fbl[j], acc[i][j], 0, 0, 0);
                acc[i][j] = __builtin_amdgcn_mfma_f32_16x16x32_f16(fal[i], fbh[j], acc[i][j], 0, 0, 0);
            }
        __syncthreads();
    }

    const float scale = 1.f / 64.f;
    #pragma unroll
    for (int i = 0; i < 4; ++i)
        #pragma unroll
        for (int j = 0; j < 3; ++j)
            #pragma unroll
            for (int r = 0; r < 4; ++r) {
                int pixLocal = wave * 64 + 16 * i + fq * 4 + r;
                int n = 16 * j + fr;
                if (n < 48)
                    outs[pixLocal * 48 + n] = fmaf(acc[i][j][r], scale, sb[n]);
            }
    __syncthreads();

    int p = tid;
    #pragma unroll
    for (int a = 0; a < 9; ++a) {
        float z   = outs[p * 48 + a];
        float dyv = outs[p * 48 + 9 + 4 * a + 0];
        float dxv = outs[p * 48 + 9 + 4 * a + 1];
        float dhv = outs[p * 48 + 9 + 4 * a + 2];
        float dwv = outs[p * 48 + 9 + 4 * a + 3];
        int gi = (h0 * 128 + p) * 9 + a;
        decode_emit(gi, z, dyv, dxv, dhv, dwv, boxes, keys, cnt, hist);
    }
}

// ---------------- fallback fp32 conv ----------------
template<int CIN, bool RELU_IN, bool RELU_OUT>
__global__ __launch_bounds__(256) void conv3x3_kernel(
    const float* __restrict__ in, const float* __restrict__ wgt,
    const float* __restrict__ bias, float* __restrict__ out)
{
    __shared__ float As[32][68];
    __shared__ float Bs[32][64];
    int bx = blockIdx.x;
    int mtile = bx & 255, ntile = bx >> 8;
    int h = mtile >> 1, w0 = (mtile & 1) << 6, n0 = ntile << 6;
    int tid = threadIdx.x, ty = tid >> 4, tx = tid & 15;
    float acc[4][4] = {{0.f}};
    const int KTOT = 9 * CIN;
    for (int k0 = 0; k0 < KTOT; k0 += 32) {
        int tap = k0 / CIN, icb = k0 % CIN;
        int dy = tap / 3 - 1, dx = tap % 3 - 1;
        int row = h + dy;
        bool rowok = ((unsigned)row < HW);
        {
            int pix = tid >> 3, cs = (tid & 7) << 2;
            #pragma unroll
            for (int p = 0; p < 2; ++p) {
                int px = pix + p * 32;
                int wcol = w0 + px + dx;
                float4 v = make_float4(0.f, 0.f, 0.f, 0.f);
                if (rowok && (unsigned)wcol < HW) {
                    v = *(const float4*)&in[((size_t)row * HW + wcol) * CIN + icb + cs];
                    if (RELU_IN) {
                        v.x = fmaxf(v.x, 0.f); v.y = fmaxf(v.y, 0.f);
                        v.z = fmaxf(v.z, 0.f); v.w = fmaxf(v.w, 0.f);
                    }
                }
                As[cs + 0][px] = v.x; As[cs + 1][px] = v.y;
                As[cs + 2][px] = v.z; As[cs + 3][px] = v.w;
            }
        }
        {
            int kr = tid >> 4, nc = (tid & 15) << 2;
            #pragma unroll
            for (int p = 0; p < 2; ++p) {
                int k = kr + p * 16;
                *(float4*)&Bs[k][nc] = *(const float4*)&wgt[(size_t)(k0 + k) * COUTC + n0 + nc];
            }
        }
        __syncthreads();
        #pragma unroll
        for (int kk = 0; kk < 32; ++kk) {
            float4 a = *(const float4*)&As[kk][ty << 2];
            float4 b = *(const float4*)&Bs[kk][tx << 2];
            float av[4] = {a.x, a.y, a.z, a.w};
            float bv[4] = {b.x, b.y, b.z, b.w};
            #pragma unroll
            for (int i = 0; i < 4; ++i)
                #pragma unroll
                for (int j = 0; j < 4; ++j)
                    acc[i][j] = fmaf(av[i], bv[j], acc[i][j]);
        }
        __syncthreads();
    }
    float4 bi = *(const float4*)&bias[n0 + (tx << 2)];
    float bv2[4] = {bi.x, bi.y, bi.z, bi.w};
    #pragma unroll
    for (int i = 0; i < 4; ++i) {
        float4 o;
        o.x = acc[i][0] + bv2[0]; o.y = acc[i][1] + bv2[1];
        o.z = acc[i][2] + bv2[2]; o.w = acc[i][3] + bv2[3];
        if (RELU_OUT) {
            o.x = fmaxf(o.x, 0.f); o.y = fmaxf(o.y, 0.f);
            o.z = fmaxf(o.z, 0.f); o.w = fmaxf(o.w, 0.f);
        }
        *(float4*)&out[((size_t)(h * HW) + w0 + (ty << 2) + i) * COUTC + n0 + (tx << 2)] = o;
    }
}

// ---------------- fallback heads ----------------
__global__ __launch_bounds__(256) void heads_decode_kernel(
    const float* __restrict__ x, const float* __restrict__ w_s, const float* __restrict__ b_s,
    const float* __restrict__ w_b, const float* __restrict__ b_b,
    float4* __restrict__ boxes, unsigned long long* __restrict__ keys,
    int* __restrict__ cnt, int* __restrict__ hist)
{
    __shared__ float xs[4][512];
    __shared__ float outs[4][45];
    int wave = threadIdx.x >> 6;
    int lane = threadIdx.x & 63;
    int pix  = blockIdx.x * 4 + wave;

    const float4* xp = (const float4*)&x[(size_t)pix * COUTC];
    *(float4*)&xs[wave][lane * 4]       = xp[lane];
    *(float4*)&xs[wave][256 + lane * 4] = xp[64 + lane];
    __syncthreads();

    if (lane < 45) {
        const float* wp; int stride; float acc;
        if (lane < 9) { wp = w_s + lane;       stride = 9;  acc = b_s[lane]; }
        else          { wp = w_b + (lane - 9); stride = 36; acc = b_b[lane - 9]; }
        const float* xrow = xs[wave];
        for (int k = 0; k < 512; k += 4) {
            acc = fmaf(xrow[k + 0], wp[(k + 0) * stride], acc);
            acc = fmaf(xrow[k + 1], wp[(k + 1) * stride], acc);
            acc = fmaf(xrow[k + 2], wp[(k + 2) * stride], acc);
            acc = fmaf(xrow[k + 3], wp[(k + 3) * stride], acc);
        }
        outs[wave][lane] = acc;
    }
    __syncthreads();

    if (lane < 9) {
        int a = lane;
        decode_emit(pix * 9 + a, outs[wave][a],
                    outs[wave][9 + 4 * a + 0], outs[wave][9 + 4 * a + 1],
                    outs[wave][9 + 4 * a + 2], outs[wave][9 + 4 * a + 3],
                    boxes, keys, cnt, hist);
    }
}

__global__ __launch_bounds__(256) void scan_kernel(
    const int* __restrict__ hist, int* __restrict__ base)
{
    __shared__ int buf[256];
    __shared__ int carry;
    int tid = threadIdx.x;
    if (tid == 0) carry = 0;
    __syncthreads();
    for (int c = 0; c < NB; c += 256) {
        int idx = c + tid;
        int v = (idx < NB) ? hist[idx] : 0;
        buf[tid] = v;
        __syncthreads();
        for (int s = 1; s < 256; s <<= 1) {
            int t = (tid >= s) ? buf[tid - s] : 0;
            __syncthreads();
            buf[tid] += t;
            __syncthreads();
        }
        if (idx < NB) base[idx] = carry + buf[tid] - v;
        __syncthreads();
        if (tid == 0) carry += buf[255];
        __syncthreads();
    }
    if (tid == 0) base[NB] = carry;
}

__global__ __launch_bounds__(256) void scatter_kernel(
    const unsigned long long* __restrict__ keys, const int* __restrict__ cnt,
    const int* __restrict__ base, int* __restrict__ cur,
    unsigned long long* __restrict__ skeys)
{
    int i = blockIdx.x * 256 + threadIdx.x;
    if (i < *cnt) {
        unsigned long long k = keys[i];
        int b = (int)(k >> 29);
        int p = base[b] + atomicAdd(&cur[b], 1);
        skeys[p] = k;
    }
}

// ---------------- per-bucket rank sort + top-T gather ----------------
__global__ __launch_bounds__(256) void sortb_kernel(
    const unsigned long long* __restrict__ skeys, const int* __restrict__ base,
    const float4* __restrict__ boxes,
    unsigned long long* __restrict__ sk2,
    float4* __restrict__ cboxes, float* __restrict__ careas)
{
    __shared__ unsigned long long sk[2048];
    int b = blockIdx.x;
    int s0 = base[b];
    int n = base[b + 1] - s0;
    if (n <= 0) return;
    int t = threadIdx.x;
    if (n <= 2048) {
        for (int i = t; i < n; i += 256) sk[i] = skeys[s0 + i];
        __syncthreads();
        for (int i = t; i < n; i += 256) {
            unsigned long long k = sk[i];
            int r = 0;
            for (int j = 0; j < n; ++j) r += (sk[j] < k) ? 1 : 0;
            int pos = s0 + r;
            sk2[pos] = k;
            if (pos < T_TOP) {
                float4 bb = boxes[k & 0x3FFFFull];
                cboxes[pos] = bb;
                careas[pos] = (bb.z - bb.x) * (bb.w - bb.y);
            }
        }
    } else {
        const unsigned long long* src = skeys + s0;
        for (int i = t; i < n; i += 256) {
            unsigned long long k = src[i];
            int r = 0;
            for (int j = 0; j < n; ++j) r += (src[j] < k) ? 1 : 0;
            int pos = s0 + r;
            sk2[pos] = k;
            if (pos < T_TOP) {
                float4 bb = boxes[k & 0x3FFFFull];
                cboxes[pos] = bb;
                careas[pos] = (bb.z - bb.x) * (bb.w - bb.y);
            }
        }
    }
}

// ---------------- pairwise suppression bitmask (T=4096) ----------------
__global__ __launch_bounds__(256) void mask_kernel(
    const float4* __restrict__ cboxes, const float* __restrict__ careas,
    unsigned long long* __restrict__ msk)
{
    int bi = blockIdx.y, bj = blockIdx.x;
    if (bj < bi) return;
    __shared__ float4 jb[256];
    __shared__ float  ja[256];
    int t = threadIdx.x;
    int j0 = bj << 8;
    jb[t] = cboxes[j0 + t];
    ja[t] = careas[j0 + t];
    __syncthreads();
    int i = (bi << 8) + t;
    float4 ci = cboxes[i];
    float ca = careas[i];
    unsigned long long word = 0;
    for (int jj = 0; jj < 256; ++jj) {
        int j = j0 + jj;
        float4 b = jb[jj];
        float iy = fmaxf(0.f, fminf(ci.z, b.z) - fmaxf(ci.x, b.x));
        float ix = fmaxf(0.f, fminf(ci.w, b.w) - fmaxf(ci.y, b.y));
        float inter = iy * ix;
        float iou = inter / (ca + ja[jj] - inter + 1e-9f);
        bool bit = (j == i) || (j > i && iou > 0.7f);
        if (bit) word |= 1ull << (jj & 63);
        if ((jj & 63) == 63) {
            msk[(size_t)i * TW + (bj << 2) + (jj >> 6)] = word;
            word = 0;
        }
    }
}

// ---------------- greedy walk over bitmask (single wave, 2-deep spec) + exact tail ----------------
__global__ __launch_bounds__(64) void walk_kernel(
    const unsigned long long* __restrict__ sk2, const int* __restrict__ cnt,
    const float4* __restrict__ cboxes, const float* __restrict__ careas,
    const unsigned long long* __restrict__ msk, const float4* __restrict__ boxes,
    float* __restrict__ out)
{
    __shared__ unsigned long long sup[TW];
    __shared__ float4 sbox[NSEL];
    __shared__ float  sarea[NSEL];
    int lane = threadIdx.x;
    for (int i = lane; i < 1800; i += 64) out[i] = 0.f;
    sup[lane] = 0ull;
    __syncthreads();

    int total = *cnt;
    int Tc = min(total, T_TOP);
    int sel = 0;

    auto scanFrom = [&](int p) -> int {
        if (p < 0 || p >= Tc) return -1;
        int w = p >> 6;
        unsigned long long f = (~sup[w]) & (~0ull << (p & 63));
        while (f == 0ull) {
            ++w;
            if (w >= TW) return -1;
            f = ~sup[w];
        }
        int c = (w << 6) + __builtin_ctzll(f);
        return (c < Tc) ? c : -1;
    };

    unsigned long long r0, r1, r2n;
    int idx = scanFrom(0);
    if (idx >= 0) r0 = msk[(size_t)idx * TW + lane];
    int idx2 = (idx >= 0) ? scanFrom(idx + 1) : -1;
    if (idx2 >= 0) r1 = msk[(size_t)idx2 * TW + lane];

    while (idx >= 0 && sel < NSEL) {
        float4 cb = cboxes[idx];
        float ca = careas[idx];
        if (lane == 0) {
            unsigned long long key = sk2[idx];
            out[sel * 4 + 0] = cb.x; out[sel * 4 + 1] = cb.y;
            out[sel * 4 + 2] = cb.z; out[sel * 4 + 3] = cb.w;
            out[1200 + sel] = __uint_as_float(0x3F800000u - (unsigned)(key >> 18));
            out[1500 + sel] = 1.f;
            sbox[sel] = cb;
            sarea[sel] = ca;
        }
        sel++;
        if (sel >= NSEL) break;

        int idx3 = (idx2 >= 0) ? scanFrom(idx2 + 1) : -1;
        if (idx3 >= 0) r2n = msk[(size_t)idx3 * TW + lane];

        sup[lane] |= r0;
        __syncthreads();

        if (idx2 >= 0) {
            unsigned long long w = sup[idx2 >> 6];
            if ((w >> (idx2 & 63)) & 1ull) {
                idx2 = scanFrom(idx2);
                if (idx2 >= 0) r1 = msk[(size_t)idx2 * TW + lane];
                idx3 = (idx2 >= 0) ? scanFrom(idx2 + 1) : -1;
                if (idx3 >= 0) r2n = msk[(size_t)idx3 * TW + lane];
            }
        }
        idx = idx2; r0 = r1;
        idx2 = idx3; r1 = r2n;
    }

    // exact tail beyond T_TOP
    if (sel < NSEL && total > T_TOP) {
        for (int i = T_TOP; i < total && sel < NSEL; ++i) {
            unsigned long long key = sk2[i];
            float4 cb = boxes[key & 0x3FFFFull];
            float ca = (cb.z - cb.x) * (cb.w - cb.y);
            int supp = 0;
            for (int t = lane; t < sel; t += 64) {
                float4 s4 = sbox[t];
                float iy = fmaxf(0.f, fminf(s4.z, cb.z) - fmaxf(s4.x, cb.x));
                float ix = fmaxf(0.f, fminf(s4.w, cb.w) - fmaxf(s4.y, cb.y));
                float inter = iy * ix;
                float iou = inter / (sarea[t] + ca - inter + 1e-9f);
                if (iou > 0.7f) supp = 1;
            }
            if (__ballot(supp) == 0ull) {
                if (lane == 0) {
                    out[sel * 4 + 0] = cb.x; out[sel * 4 + 1] = cb.y;
                    out[sel * 4 + 2] = cb.z; out[sel * 4 + 3] = cb.w;
                    out[1200 + sel] = __uint_as_float(0x3F800000u - (unsigned)(key >> 18));
                    out[1500 + sel] = 1.f;
                    sbox[sel] = cb;
                    sarea[sel] = ca;
                }
                sel++;
            }
        }
    }
}

extern "C" void kernel_launch(void* const* d_in, const int* in_sizes, int n_in,
                              void* d_out, int out_size, void* d_ws, size_t ws_size,
                              hipStream_t stream) {
    const float* feat = (const float*)d_in[0];
    const float* w1   = (const float*)d_in[1];
    const float* b1   = (const float*)d_in[2];
    const float* w2   = (const float*)d_in[3];
    const float* b2   = (const float*)d_in[4];
    const float* w_s  = (const float*)d_in[5];
    const float* b_s  = (const float*)d_in[6];
    const float* w_b  = (const float*)d_in[7];
    const float* b_b  = (const float*)d_in[8];
    float* out = (float*)d_out;
    char* ws = (char*)d_ws;

    if (ws_size >= NWS_TOTAL) {
        _Float16* a1h = (_Float16*)(ws + NWS_A1H);
        _Float16* a1l = (_Float16*)(ws + NWS_A1L);
        _Float16* w1h = (_Float16*)(ws + NWS_W1H);
        _Float16* w1l = (_Float16*)(ws + NWS_W1L);
        _Float16* a2h = (_Float16*)(ws + NWS_A2H);
        _Float16* a2l = (_Float16*)(ws + NWS_A2L);
        _Float16* w2h = (_Float16*)(ws + NWS_W2H);
        _Float16* w2l = (_Float16*)(ws + NWS_W2L);
        _Float16* xh  = (_Float16*)(ws + NWS_X2);
        _Float16* xl  = (_Float16*)(ws + NWS_X2 + 16777216);
        float4* boxes = (float4*)(ws + NWS_BOXES);
        unsigned long long* keys  = (unsigned long long*)(ws + NWS_KEYS);
        unsigned long long* skeys = (unsigned long long*)(ws + NWS_SKEYS);
        int* hist = (int*)(ws + NWS_HIST);
        int* cur  = (int*)(ws + NWS_CUR);
        int* cnt  = (int*)(ws + NWS_CNT);
        int* base = (int*)(ws + NWS_BASE);
        _Float16* wbh = (_Float16*)(ws + NWS_SKEYS);           // dead before scatter writes skeys
        _Float16* wbl = (_Float16*)(ws + NWS_SKEYS + 65536);
        unsigned long long* msk = (unsigned long long*)(ws + NWS_A1H);   // 2 MB now
        float4* cbox  = (float4*)(ws + NWS_A1L);
        float*  carea = (float*)(ws + NWS_A1L + 262144);
        unsigned long long* sk2 = keys;

        hipMemsetAsync(ws + NWS_HIST, 0, (NWS_CNT - NWS_HIST) + 256, stream);
        convert_feat_kernel<<<16900, 256, 0, stream>>>(feat, a1h, a1l);
        prep_kernel<<<4100, 256, 0, stream>>>(w1, w1h, w1l, w2, w2h, w2l,
                                              w_s, w_b, wbh, wbl, a2h, a2l);
        conv_mfma_kernel<1024, true ><<<512, 256, 0, stream>>>(a1h, a1l, w1h, w1l, b1, a2h, a2l);
        conv_mfma_kernel< 512, false><<<512, 256, 0, stream>>>(a2h, a2l, w2h, w2l, b2, xh, xl);
        heads_mfma_kernel<<<64, 256, 0, stream>>>(xh, xl, wbh, wbl, b_s, b_b, boxes, keys, cnt, hist);
        scan_kernel<<<1, 256, 0, stream>>>(hist, base);
        scatter_kernel<<<576, 256, 0, stream>>>(keys, cnt, base, cur, skeys);
        sortb_kernel<<<NB, 256, 0, stream>>>(skeys, base, boxes, sk2, cbox, carea);
        mask_kernel<<<dim3(16, 16), 256, 0, stream>>>(cbox, carea, msk);
        walk_kernel<<<1, 64, 0, stream>>>(sk2, cnt, cbox, carea, msk, boxes, out);
    } else {
        float* x1 = (float*)(ws + WS_X1);
        float* x2 = (float*)(ws + WS_X2);
        float4* boxes = (float4*)(ws + WS_BOXES);
        unsigned long long* keys  = (unsigned long long*)(ws + WS_KEYS);
        unsigned long long* skeys = (unsigned long long*)(ws + WS_SKEYS);
        int* hist = (int*)(ws + WS_HIST);
        int* cur  = (int*)(ws + WS_CUR);
        int* cnt  = (int*)(ws + WS_CNT);
        int* base = (int*)(ws + WS_BASE);
        unsigned long long* msk = (unsigned long long*)(ws + WS_X1);
        float4* cbox  = (float4*)(ws + WS_X2);
        float*  carea = (float*)(ws + WS_X2 + 262144);
        unsigned long long* sk2 = keys;

        hipMemsetAsync(ws + WS_HIST, 0, (WS_CNT - WS_HIST) + 256, stream);
        conv3x3_kernel<1024, true,  true ><<<2048, 256, 0, stream>>>(feat, w1, b1, x1);
        conv3x3_kernel< 512, false, false><<<2048, 256, 0, stream>>>(x1,   w2, b2, x2);
        heads_decode_kernel<<<4096, 256, 0, stream>>>(x2, w_s, b_s, w_b, b_b, boxes, keys, cnt, hist);
        scan_kernel<<<1, 256, 0, stream>>>(hist, base);
        scatter_kernel<<<576, 256, 0, stream>>>(keys, cnt, base, cur, skeys);
        sortb_kernel<<<NB, 256, 0, stream>>>(skeys, base, boxes, sk2, cbox, carea);
        mask_kernel<<<dim3(16, 16), 256, 0, stream>>>(cbox, carea, msk);
        walk_kernel<<<1, 64, 0, stream>>>(sk2, cnt, cbox, carea, msk, boxes, out);
    }
}

// Round 8
// 871.320 us; speedup vs baseline: 1.5854x; 1.1644x over previous
//
#include <hip/hip_runtime.h>

#define HW 128
#define COUTC 512
#define NB 4097
#define NSEL 300
#define T_TOP 4096
#define TW 64           // words per mask row = T_TOP/64
#define FAST_N 1024

typedef _Float16 half8 __attribute__((ext_vector_type(8)));
typedef _Float16 half4v __attribute__((ext_vector_type(4)));
typedef float floatx4 __attribute__((ext_vector_type(4)));

// ================= fast-path ws layout (bytes) =================
#define NWS_A1H   ((size_t)0)            // 34,611,200  (dead after conv1 -> MSK 2MB)
#define NWS_A1L   ((size_t)34611200)     // (dead after conv1 -> CBOX/CAREA)
#define NWS_W1H   ((size_t)69222400)
#define NWS_W1L   ((size_t)78659584)
#define NWS_A2H   ((size_t)88096768)
#define NWS_A2L   ((size_t)105402368)
#define NWS_W2H   ((size_t)122707968)
#define NWS_W2L   ((size_t)127426560)
#define NWS_X2    ((size_t)132145152)    // xh (16,777,216) + xl (16,777,216)
#define NWS_BOXES ((size_t)165699584)
#define NWS_KEYS  ((size_t)168058880)    // reused as sorted keys (sk2)
#define NWS_SKEYS ((size_t)169238528)    // wbh/wbl live here until heads done
#define NWS_HIST  ((size_t)170418176)
#define NWS_CUR   ((size_t)170434816)
#define NWS_CNT   ((size_t)170451456)
#define NWS_BASE  ((size_t)170451712)
#define NWS_TOTAL ((size_t)170468352)

// ================= fallback ws layout =================
#define WS_X1     ((size_t)0)
#define WS_X2     ((size_t)33554432)
#define WS_BOXES  ((size_t)67108864)
#define WS_KEYS   ((size_t)69468160)
#define WS_SKEYS  ((size_t)70647808)
#define WS_HIST   ((size_t)71827456)
#define WS_CUR    ((size_t)71844096)
#define WS_CNT    ((size_t)71860736)
#define WS_BASE   ((size_t)71860992)

__device__ __forceinline__ void glds16(const void* g, void* l) {
    __builtin_amdgcn_global_load_lds(
        (const __attribute__((address_space(1))) void*)g,
        (__attribute__((address_space(3))) void*)l, 16, 0, 0);
}

// Activation layout (per padded row pr): [chunk(CIN/32)][sub(4)][pc(130)][8ch]
// Weight layout (per tap): [chunk(CIN/32)][sub(4)][oc(512)][8ch]
// conv2-output (heads input) layout (per row h): [chunk(16)][sub(4)][pix(128)][8ch], rowstride 65536 halves

// ---------------- feature convert: LDS transpose, coalesced both ways ----------------
__global__ __launch_bounds__(256) void convert_feat_kernel(
    const float* __restrict__ feat, _Float16* __restrict__ ah, _Float16* __restrict__ al)
{
    __shared__ __align__(16) _Float16 lh[130 * 32];
    __shared__ __align__(16) _Float16 ll[130 * 32];
    int pr = blockIdx.x;        // 0..129
    int chunk = blockIdx.y;     // 0..31
    int t = threadIdx.x;
    int c  = t & 31;
    int pg = t >> 5;            // 0..7
    bool interior = (pr >= 1 && pr <= 128);
    if (interior) {
        for (int px = pg; px < 128; px += 8) {
            float x = feat[((size_t)(pr - 1) * 128 + px) * 1024 + chunk * 32 + c];
            x = fmaxf(x, 0.f);
            _Float16 hi = (_Float16)x;
            lh[(px + 1) * 32 + c] = hi;
            ll[(px + 1) * 32 + c] = (_Float16)(x - (float)hi);
        }
    } else {
        for (int px = pg; px < 128; px += 8) {
            lh[(px + 1) * 32 + c] = (_Float16)0.f;
            ll[(px + 1) * 32 + c] = (_Float16)0.f;
        }
    }
    if (t < 32) {
        lh[t] = (_Float16)0.f;          ll[t] = (_Float16)0.f;
        lh[129 * 32 + t] = (_Float16)0.f; ll[129 * 32 + t] = (_Float16)0.f;
    }
    __syncthreads();
    size_t base = (size_t)pr * 133120 + (size_t)chunk * 4160;
    for (int i = t; i < 520; i += 256) {
        int sub = i / 130;
        int pc  = i - sub * 130;
        *(float4*)&ah[base + sub * 1040 + pc * 8] = *(const float4*)&lh[pc * 32 + sub * 8];
        *(float4*)&al[base + sub * 1040 + pc * 8] = *(const float4*)&ll[pc * 32 + sub * 8];
    }
}

// ---------------- fused prep: conv weights + head weights + a2 pad ring ----------------
template<int CIN>
__device__ __forceinline__ void convert_w_body(
    int b, const float* __restrict__ w, _Float16* __restrict__ wh, _Float16* __restrict__ wl)
{
    constexpr int NU = CIN / 8;
    int gid = b * 256 + threadIdx.x;
    int oc = gid & 511;
    int rest = gid >> 9;
    int u = rest & (NU - 1);
    int tap = rest / NU;
    if (tap >= 9) return;
    int k0 = u * 8;
    half8 vh, vl;
    #pragma unroll
    for (int j = 0; j < 8; ++j) {
        float v = w[((size_t)tap * CIN + k0 + j) * 512 + oc] * 64.f;
        _Float16 hi = (_Float16)v;
        vh[j] = hi;
        vl[j] = (_Float16)(v - (float)hi);
    }
    size_t o = (size_t)tap * CIN * 512 + (size_t)(k0 >> 5) * 16384
             + (size_t)((k0 >> 3) & 3) * 4096 + (size_t)oc * 8;
    *(half8*)(wh + o) = vh;
    *(half8*)(wl + o) = vl;
}

__global__ __launch_bounds__(256) void prep_kernel(
    const float* __restrict__ w1, _Float16* __restrict__ w1h, _Float16* __restrict__ w1l,
    const float* __restrict__ w2, _Float16* __restrict__ w2h, _Float16* __restrict__ w2l,
    const float* __restrict__ w_s, const float* __restrict__ w_b,
    _Float16* __restrict__ wbh, _Float16* __restrict__ wbl,
    _Float16* __restrict__ a2h, _Float16* __restrict__ a2l)
{
    int b = blockIdx.x;
    if (b < 2304) { convert_w_body<1024>(b, w1, w1h, w1l); return; }
    if (b < 3456) { convert_w_body<512>(b - 2304, w2, w2h, w2l); return; }
    if (b < 3584) {
        int gid = (b - 3456) * 256 + threadIdx.x;    // 32768 = 64n x 512k
        int n = gid & 63;
        int k = gid >> 6;
        float v = 0.f;
        if (n < 9)       v = w_s[k * 9 + n] * 64.f;
        else if (n < 45) v = w_b[k * 36 + (n - 9)] * 64.f;
        _Float16 hi = (_Float16)v;
        size_t o = (size_t)(k >> 5) * 2048 + (size_t)((k >> 3) & 3) * 512 + (size_t)n * 8 + (k & 7);
        wbh[o] = hi;
        wbl[o] = (_Float16)(v - (float)hi);
        return;
    }
    {   // a2 pad ring (516 blocks)
        int i = b - 3584;
        int pr, pc;
        if (i < 130)      { pr = 0;        pc = i; }
        else if (i < 260) { pr = 129;      pc = i - 130; }
        else if (i < 388) { pr = i - 259;  pc = 0; }
        else              { pr = i - 387;  pc = 129; }
        int t = threadIdx.x;
        if (t >= 128) return;
        _Float16* dst = (t & 64) ? a2l : a2h;
        int u = t & 63;
        size_t o = (size_t)pr * 66560 + (size_t)(u >> 2) * 4160 + (size_t)(u & 3) * 1040 + (size_t)pc * 8;
        *(float4*)(dst + o) = make_float4(0.f, 0.f, 0.f, 0.f);
    }
}

// ---------------- conv 3x3 fp16-split MFMA, BK=64 ----------------
template<int CIN, bool PAD>
__global__ __launch_bounds__(256) void conv_mfma_kernel(
    const _Float16* __restrict__ ah, const _Float16* __restrict__ al,
    const _Float16* __restrict__ wh, const _Float16* __restrict__ wl,
    const float* __restrict__ bias,
    _Float16* __restrict__ oh, _Float16* __restrict__ ol)
{
    constexpr int ROWSTR = CIN * 130;
    constexpr int TAPW   = CIN * 512;
    __shared__ __align__(16) _Float16 lds[32768];

    int bx = blockIdx.x;
    int h  = bx & 127;
    int n0 = (bx >> 7) << 7;

    int tid  = threadIdx.x;
    int wave = tid >> 6;
    int lane = tid & 63;
    int fr = lane & 15;
    int fq = lane >> 4;

    int aoff0 = fq * 1040 + (32 * wave + fr) * 8;
    int aoff1 = aoff0 + 128;
    int boff0 = fq * 4096 + (n0 + 32 * wave + fr) * 8;
    int boff1 = boff0 + 128;

    int wm = wave & 1, wn = wave >> 1;

    floatx4 acc[4][4];
    #pragma unroll
    for (int i = 0; i < 4; ++i)
        #pragma unroll
        for (int j = 0; j < 4; ++j)
            acc[i][j] = (floatx4){0.f, 0.f, 0.f, 0.f};

    #pragma unroll
    for (int tap = 0; tap < 9; ++tap) {
        int dy = tap / 3 - 1, dx = tap % 3 - 1;
        const _Float16* gAh = ah + (size_t)(h + dy + 1) * ROWSTR + (dx + 1) * 8;
        const _Float16* gAl = al + (size_t)(h + dy + 1) * ROWSTR + (dx + 1) * 8;
        const _Float16* gBh = wh + (size_t)tap * TAPW;
        const _Float16* gBl = wl + (size_t)tap * TAPW;

        for (int kc = 0; kc < CIN; kc += 64) {
            #pragma unroll
            for (int s = 0; s < 2; ++s) {
                int ab = ((kc >> 5) + s) * 4160;
                int bb = ((kc >> 5) + s) * 16384;
                _Float16* A0 = lds +          s * 4096 + 2 * wave * 512;
                _Float16* L0 = lds + 8192  +  s * 4096 + 2 * wave * 512;
                _Float16* B0 = lds + 16384 +  s * 4096 + 2 * wave * 512;
                _Float16* C0 = lds + 24576 +  s * 4096 + 2 * wave * 512;
                glds16(gAh + ab + aoff0, A0);
                glds16(gAh + ab + aoff1, A0 + 512);
                glds16(gAl + ab + aoff0, L0);
                glds16(gAl + ab + aoff1, L0 + 512);
                glds16(gBh + bb + boff0, B0);
                glds16(gBh + bb + boff1, B0 + 512);
                glds16(gBl + bb + boff0, C0);
                glds16(gBl + bb + boff1, C0 + 512);
            }
            __syncthreads();

            #pragma unroll
            for (int s = 0; s < 2; ++s) {
                const _Float16* rAh = lds +          s * 4096 + wm * 2048 + fq * 128 + fr * 8;
                const _Float16* rAl = rAh + 8192;
                const _Float16* rBh = lds + 16384 +  s * 4096 + wn * 2048 + fq * 128 + fr * 8;
                const _Float16* rBl = rBh + 8192;

                half8 fah[4], fal[4], fbh[4], fbl[4];
                #pragma unroll
                for (int i = 0; i < 4; ++i) {
                    fah[i] = *(const half8*)(rAh + i * 512);
                    fal[i] = *(const half8*)(rAl + i * 512);
                    fbh[i] = *(const half8*)(rBh + i * 512);
                    fbl[i] = *(const half8*)(rBl + i * 512);
                }
                #pragma unroll
                for (int i = 0; i < 4; ++i)
                    #pragma unroll
                    for (int j = 0; j < 4; ++j)
                        acc[i][j] = __builtin_amdgcn_mfma_f32_16x16x32_f16(fah[i], fbh[j], acc[i][j], 0, 0, 0);
                #pragma unroll
                for (int i = 0; i < 4; ++i)
                    #pragma unroll
                    for (int j = 0; j < 4; ++j)
                        acc[i][j] = __builtin_amdgcn_mfma_f32_16x16x32_f16(fah[i], fbl[j], acc[i][j], 0, 0, 0);
                #pragma unroll
                for (int i = 0; i < 4; ++i)
                    #pragma unroll
                    for (int j = 0; j < 4; ++j)
                        acc[i][j] = __builtin_amdgcn_mfma_f32_16x16x32_f16(fal[i], fbh[j], acc[i][j], 0, 0, 0);
            }
            __syncthreads();
        }
    }

    const float scale = 1.f / 64.f;
    int em = 64 * wm + fq * 4;
    int en = 64 * wn + fr;
    #pragma unroll
    for (int j = 0; j < 4; ++j) {
        int oc = n0 + en + 16 * j;
        float b = bias[oc];
        #pragma unroll
        for (int i = 0; i < 4; ++i) {
            #pragma unroll
            for (int r = 0; r < 4; ++r) {
                int w = em + 16 * i + r;
                float v = fmaf(acc[i][j][r], scale, b);
                if (PAD) {
                    v = fmaxf(v, 0.f);
                    _Float16 hi = (_Float16)v;
                    size_t o = (size_t)(h + 1) * 66560 + (size_t)(oc >> 5) * 4160
                             + (size_t)((oc >> 3) & 3) * 1040 + (size_t)(w + 1) * 8 + (oc & 7);
                    oh[o] = hi;
                    ol[o] = (_Float16)(v - (float)hi);
                } else {
                    _Float16 hi = (_Float16)v;
                    size_t o = (size_t)h * 65536 + (size_t)(oc >> 5) * 4096
                             + (size_t)((oc >> 3) & 3) * 1024 + (size_t)w * 8 + (oc & 7);
                    oh[o] = hi;
                    ol[o] = (_Float16)(v - (float)hi);
                }
            }
        }
    }
}

// ---------------- decode helper ----------------
__device__ __forceinline__ void decode_emit(
    int gi, float z, float dyv, float dxv, float dhv, float dwv,
    float4* __restrict__ boxes, unsigned long long* __restrict__ keys,
    int* __restrict__ cnt, int* __restrict__ hist)
{
    int a = gi % 9;
    int pix = gi / 9;
    int h = pix >> 7, w = pix & 127;
    float sc  = (a < 3) ? 128.f : ((a < 6) ? 256.f : 512.f);
    int r = a - (a / 3) * 3;
    float ratio = (r == 0) ? 0.5f : ((r == 1) ? 1.f : 2.f);
    float sr = sqrtf(ratio);
    float ahh = sc * sr, aww = sc / sr;
    float acy = ((float)h + 0.5f) * 16.f;
    float acx = ((float)w + 0.5f) * 16.f;
    float cy = fmaf(dyv, ahh, acy);
    float cx = fmaf(dxv, aww, acx);
    float hh = ahh * expf(dhv);
    float ww = aww * expf(dwv);
    float y1 = fminf(fmaxf(cy - 0.5f * hh, 0.f), 2048.f);
    float x1 = fminf(fmaxf(cx - 0.5f * ww, 0.f), 2048.f);
    float y2 = fminf(fmaxf(cy + 0.5f * hh, 0.f), 2048.f);
    float x2 = fminf(fmaxf(cx + 0.5f * ww, 0.f), 2048.f);
    boxes[gi] = make_float4(y1, x1, y2, x2);
    float s = 1.f / (1.f + expf(-z));
    if (s >= 0.5f) {
        unsigned u = __float_as_uint(s);
        unsigned d = 0x3F800000u - u;
        unsigned long long key = ((unsigned long long)d << 18) | (unsigned)gi;
        int p = atomicAdd(cnt, 1);
        keys[p] = key;
        atomicAdd(&hist[d >> 11], 1);
    }
}

// ---------------- heads via MFMA: 128 blocks, M=128 px, N=48(pad 64), K=512 ----------------
__global__ __launch_bounds__(256) void heads_mfma_kernel(
    const _Float16* __restrict__ xh, const _Float16* __restrict__ xl,
    const _Float16* __restrict__ wbh, const _Float16* __restrict__ wbl,
    const float* __restrict__ b_s, const float* __restrict__ b_b,
    float4* __restrict__ boxes, unsigned long long* __restrict__ keys,
    int* __restrict__ cnt, int* __restrict__ hist)
{
    __shared__ __align__(16) char smem[24576];
    _Float16* sAh = (_Float16*)smem;             // 4096 halves: [sub4][pix128][8]
    _Float16* sAl = (_Float16*)(smem + 8192);
    _Float16* sBh = (_Float16*)(smem + 16384);   // 2048 halves: [sub4][n64][8]
    _Float16* sBl = (_Float16*)(smem + 20480);
    float* outs = (float*)smem;                  // overlay after K-loop: [128][48] = 24576 B
    __shared__ float sb[48];

    int tid  = threadIdx.x;
    int wave = tid >> 6;
    int lane = tid & 63;
    int fr = lane & 15;
    int fq = lane >> 4;
    if (tid < 48) sb[tid] = (tid < 9) ? b_s[tid] : ((tid < 45) ? b_b[tid - 9] : 0.f);

    int h = blockIdx.x;
    int wm = wave & 1, wn = wave >> 1;

    floatx4 acc[4][2];
    #pragma unroll
    for (int i = 0; i < 4; ++i)
        #pragma unroll
        for (int j = 0; j < 2; ++j)
            acc[i][j] = (floatx4){0.f, 0.f, 0.f, 0.f};

    for (int kc = 0; kc < 16; ++kc) {
        const _Float16* gxh = xh + (size_t)h * 65536 + kc * 4096;
        const _Float16* gxl = xl + (size_t)h * 65536 + kc * 4096;
        glds16(gxh + tid * 8,        sAh + tid * 8);
        glds16(gxh + 2048 + tid * 8, sAh + 2048 + tid * 8);
        glds16(gxl + tid * 8,        sAl + tid * 8);
        glds16(gxl + 2048 + tid * 8, sAl + 2048 + tid * 8);
        glds16(wbh + kc * 2048 + tid * 8, sBh + tid * 8);
        glds16(wbl + kc * 2048 + tid * 8, sBl + tid * 8);
        __syncthreads();

        half8 fah[4], fal[4], fbh[2], fbl[2];
        #pragma unroll
        for (int i = 0; i < 4; ++i) {
            int px = wm * 64 + 16 * i + fr;
            int aaddr = fq * 1024 + px * 8;
            fah[i] = *(const half8*)(sAh + aaddr);
            fal[i] = *(const half8*)(sAl + aaddr);
        }
        #pragma unroll
        for (int j = 0; j < 2; ++j) {
            int n = wn * 32 + 16 * j + fr;
            int baddr = fq * 512 + n * 8;
            fbh[j] = *(const half8*)(sBh + baddr);
            fbl[j] = *(const half8*)(sBl + baddr);
        }
        #pragma unroll
        for (int i = 0; i < 4; ++i)
            #pragma unroll
            for (int j = 0; j < 2; ++j) {
                acc[i][j] = __builtin_amdgcn_mfma_f32_16x16x32_f16(fah[i], fbh[j], acc[i][j], 0, 0, 0);
                acc[i][j] = __builtin_amdgcn_mfma_f32_16x16x32_f16(fah[i], fbl[j], acc[i][j], 0, 0, 0);
                acc[i][j] = __builtin_amdgcn_mfma_f32_16x16x32_f16(fal[i], fbh[j], acc[i][j], 0, 0, 0);
            }
        __syncthreads();
    }

    const float scale = 1.f / 64.f;
    #pragma unroll
    for (int i = 0; i < 4; ++i)
        #pragma unroll
        for (int j = 0; j < 2; ++j)
            #pragma unroll
            for (int r = 0; r < 4; ++r) {
                int px = wm * 64 + 16 * i + fq * 4 + r;
                int n = wn * 32 + 16 * j + fr;
                if (n < 48)
                    outs[px * 48 + n] = fmaf(acc[i][j][r], scale, sb[n]);
            }
    __syncthreads();

    if (tid < 128) {
        int p = tid;
        #pragma unroll
        for (int a = 0; a < 9; ++a) {
            float z   = outs[p * 48 + a];
            float dyv = outs[p * 48 + 9 + 4 * a + 0];
            float dxv = outs[p * 48 + 9 + 4 * a + 1];
            float dhv = outs[p * 48 + 9 + 4 * a + 2];
            float dwv = outs[p * 48 + 9 + 4 * a + 3];
            int gi = (h * 128 + p) * 9 + a;
            decode_emit(gi, z, dyv, dxv, dhv, dwv, boxes, keys, cnt, hist);
        }
    }
}

// ---------------- fallback fp32 conv ----------------
template<int CIN, bool RELU_IN, bool RELU_OUT>
__global__ __launch_bounds__(256) void conv3x3_kernel(
    const float* __restrict__ in, const float* __restrict__ wgt,
    const float* __restrict__ bias, float* __restrict__ out)
{
    __shared__ float As[32][68];
    __shared__ float Bs[32][64];
    int bx = blockIdx.x;
    int mtile = bx & 255, ntile = bx >> 8;
    int h = mtile >> 1, w0 = (mtile & 1) << 6, n0 = ntile << 6;
    int tid = threadIdx.x, ty = tid >> 4, tx = tid & 15;
    float acc[4][4] = {{0.f}};
    const int KTOT = 9 * CIN;
    for (int k0 = 0; k0 < KTOT; k0 += 32) {
        int tap = k0 / CIN, icb = k0 % CIN;
        int dy = tap / 3 - 1, dx = tap % 3 - 1;
        int row = h + dy;
        bool rowok = ((unsigned)row < HW);
        {
            int pix = tid >> 3, cs = (tid & 7) << 2;
            #pragma unroll
            for (int p = 0; p < 2; ++p) {
                int px = pix + p * 32;
                int wcol = w0 + px + dx;
                float4 v = make_float4(0.f, 0.f, 0.f, 0.f);
                if (rowok && (unsigned)wcol < HW) {
                    v = *(const float4*)&in[((size_t)row * HW + wcol) * CIN + icb + cs];
                    if (RELU_IN) {
                        v.x = fmaxf(v.x, 0.f); v.y = fmaxf(v.y, 0.f);
                        v.z = fmaxf(v.z, 0.f); v.w = fmaxf(v.w, 0.f);
                    }
                }
                As[cs + 0][px] = v.x; As[cs + 1][px] = v.y;
                As[cs + 2][px] = v.z; As[cs + 3][px] = v.w;
            }
        }
        {
            int kr = tid >> 4, nc = (tid & 15) << 2;
            #pragma unroll
            for (int p = 0; p < 2; ++p) {
                int k = kr + p * 16;
                *(float4*)&Bs[k][nc] = *(const float4*)&wgt[(size_t)(k0 + k) * COUTC + n0 + nc];
            }
        }
        __syncthreads();
        #pragma unroll
        for (int kk = 0; kk < 32; ++kk) {
            float4 a = *(const float4*)&As[kk][ty << 2];
            float4 b = *(const float4*)&Bs[kk][tx << 2];
            float av[4] = {a.x, a.y, a.z, a.w};
            float bv[4] = {b.x, b.y, b.z, b.w};
            #pragma unroll
            for (int i = 0; i < 4; ++i)
                #pragma unroll
                for (int j = 0; j < 4; ++j)
                    acc[i][j] = fmaf(av[i], bv[j], acc[i][j]);
        }
        __syncthreads();
    }
    float4 bi = *(const float4*)&bias[n0 + (tx << 2)];
    float bv2[4] = {bi.x, bi.y, bi.z, bi.w};
    #pragma unroll
    for (int i = 0; i < 4; ++i) {
        float4 o;
        o.x = acc[i][0] + bv2[0]; o.y = acc[i][1] + bv2[1];
        o.z = acc[i][2] + bv2[2]; o.w = acc[i][3] + bv2[3];
        if (RELU_OUT) {
            o.x = fmaxf(o.x, 0.f); o.y = fmaxf(o.y, 0.f);
            o.z = fmaxf(o.z, 0.f); o.w = fmaxf(o.w, 0.f);
        }
        *(float4*)&out[((size_t)(h * HW) + w0 + (ty << 2) + i) * COUTC + n0 + (tx << 2)] = o;
    }
}

// ---------------- fallback heads ----------------
__global__ __launch_bounds__(256) void heads_decode_kernel(
    const float* __restrict__ x, const float* __restrict__ w_s, const float* __restrict__ b_s,
    const float* __restrict__ w_b, const float* __restrict__ b_b,
    float4* __restrict__ boxes, unsigned long long* __restrict__ keys,
    int* __restrict__ cnt, int* __restrict__ hist)
{
    __shared__ float xs[4][512];
    __shared__ float outs[4][45];
    int wave = threadIdx.x >> 6;
    int lane = threadIdx.x & 63;
    int pix  = blockIdx.x * 4 + wave;

    const float4* xp = (const float4*)&x[(size_t)pix * COUTC];
    *(float4*)&xs[wave][lane * 4]       = xp[lane];
    *(float4*)&xs[wave][256 + lane * 4] = xp[64 + lane];
    __syncthreads();

    if (lane < 45) {
        const float* wp; int stride; float acc;
        if (lane < 9) { wp = w_s + lane;       stride = 9;  acc = b_s[lane]; }
        else          { wp = w_b + (lane - 9); stride = 36; acc = b_b[lane - 9]; }
        const float* xrow = xs[wave];
        for (int k = 0; k < 512; k += 4) {
            acc = fmaf(xrow[k + 0], wp[(k + 0) * stride], acc);
            acc = fmaf(xrow[k + 1], wp[(k + 1) * stride], acc);
            acc = fmaf(xrow[k + 2], wp[(k + 2) * stride], acc);
            acc = fmaf(xrow[k + 3], wp[(k + 3) * stride], acc);
        }
        outs[wave][lane] = acc;
    }
    __syncthreads();

    if (lane < 9) {
        int a = lane;
        decode_emit(pix * 9 + a, outs[wave][a],
                    outs[wave][9 + 4 * a + 0], outs[wave][9 + 4 * a + 1],
                    outs[wave][9 + 4 * a + 2], outs[wave][9 + 4 * a + 3],
                    boxes, keys, cnt, hist);
    }
}

// ---------------- scan: 16 elems/thread serial + one block scan ----------------
__global__ __launch_bounds__(256) void scan_kernel(
    const int* __restrict__ hist, int* __restrict__ base)
{
    __shared__ int tot[256];
    int t = threadIdx.x;
    int v[16];
    int s = 0;
    #pragma unroll
    for (int i = 0; i < 16; ++i) { v[i] = hist[t * 16 + i]; s += v[i]; }
    tot[t] = s;
    __syncthreads();
    for (int d = 1; d < 256; d <<= 1) {
        int x = (t >= d) ? tot[t - d] : 0;
        __syncthreads();
        tot[t] += x;
        __syncthreads();
    }
    int excl = (t == 0) ? 0 : tot[t - 1];
    #pragma unroll
    for (int i = 0; i < 16; ++i) { base[t * 16 + i] = excl; excl += v[i]; }
    if (t == 255) { base[4096] = excl; base[4097] = excl + hist[4096]; }
}

__global__ __launch_bounds__(256) void scatter_kernel(
    const unsigned long long* __restrict__ keys, const int* __restrict__ cnt,
    const int* __restrict__ base, int* __restrict__ cur,
    unsigned long long* __restrict__ skeys)
{
    int i = blockIdx.x * 256 + threadIdx.x;
    if (i < *cnt) {
        unsigned long long k = keys[i];
        int b = (int)(k >> 29);
        int p = base[b] + atomicAdd(&cur[b], 1);
        skeys[p] = k;
    }
}

// ---------------- per-bucket rank sort + top-T gather ----------------
__global__ __launch_bounds__(256) void sortb_kernel(
    const unsigned long long* __restrict__ skeys, const int* __restrict__ base,
    const float4* __restrict__ boxes,
    unsigned long long* __restrict__ sk2,
    float4* __restrict__ cboxes, float* __restrict__ careas)
{
    __shared__ unsigned long long sk[2048];
    int b = blockIdx.x;
    int s0 = base[b];
    int n = base[b + 1] - s0;
    if (n <= 0) return;
    int t = threadIdx.x;
    if (n <= 2048) {
        for (int i = t; i < n; i += 256) sk[i] = skeys[s0 + i];
        __syncthreads();
        for (int i = t; i < n; i += 256) {
            unsigned long long k = sk[i];
            int r = 0;
            for (int j = 0; j < n; ++j) r += (sk[j] < k) ? 1 : 0;
            int pos = s0 + r;
            sk2[pos] = k;
            if (pos < T_TOP) {
                float4 bb = boxes[k & 0x3FFFFull];
                cboxes[pos] = bb;
                careas[pos] = (bb.z - bb.x) * (bb.w - bb.y);
            }
        }
    } else {
        const unsigned long long* src = skeys + s0;
        for (int i = t; i < n; i += 256) {
            unsigned long long k = src[i];
            int r = 0;
            for (int j = 0; j < n; ++j) r += (src[j] < k) ? 1 : 0;
            int pos = s0 + r;
            sk2[pos] = k;
            if (pos < T_TOP) {
                float4 bb = boxes[k & 0x3FFFFull];
                cboxes[pos] = bb;
                careas[pos] = (bb.z - bb.x) * (bb.w - bb.y);
            }
        }
    }
}

// ---------------- pairwise suppression bitmask (T=4096) ----------------
__global__ __launch_bounds__(256) void mask_kernel(
    const float4* __restrict__ cboxes, const float* __restrict__ careas,
    unsigned long long* __restrict__ msk)
{
    int bi = blockIdx.y, bj = blockIdx.x;
    if (bj < bi) return;
    __shared__ float4 jb[256];
    __shared__ float  ja[256];
    int t = threadIdx.x;
    int j0 = bj << 8;
    jb[t] = cboxes[j0 + t];
    ja[t] = careas[j0 + t];
    __syncthreads();
    int i = (bi << 8) + t;
    float4 ci = cboxes[i];
    float ca = careas[i];
    unsigned long long word = 0;
    for (int jj = 0; jj < 256; ++jj) {
        int j = j0 + jj;
        float4 b = jb[jj];
        float iy = fmaxf(0.f, fminf(ci.z, b.z) - fmaxf(ci.x, b.x));
        float ix = fmaxf(0.f, fminf(ci.w, b.w) - fmaxf(ci.y, b.y));
        float inter = iy * ix;
        float iou = inter / (ca + ja[jj] - inter + 1e-9f);
        bool bit = (j == i) || (j > i && iou > 0.7f);
        if (bit) word |= 1ull << (jj & 63);
        if ((jj & 63) == 63) {
            msk[(size_t)i * TW + (bj << 2) + (jj >> 6)] = word;
            word = 0;
        }
    }
}

// ---------------- greedy walk: LDS-resident fast path + exact fallbacks ----------------
__global__ __launch_bounds__(256) void walk_kernel(
    const unsigned long long* __restrict__ sk2, const int* __restrict__ cnt,
    const float4* __restrict__ cboxes, const float* __restrict__ careas,
    const unsigned long long* __restrict__ msk, const float4* __restrict__ boxes,
    float* __restrict__ out)
{
    __shared__ unsigned long long mlds[FAST_N * 16];   // 128 KB
    __shared__ unsigned long long sup[TW];
    __shared__ float4 sbox[NSEL];
    __shared__ float  sarea[NSEL];
    __shared__ unsigned short sellist[NSEL];
    int tid = threadIdx.x;
    for (int i = tid; i < 1800; i += 256) out[i] = 0.f;
    int total = *cnt;
    int Tc = min(total, T_TOP);
    int FN = min(Tc, FAST_N);
    for (int i = tid; i < FN * 16; i += 256) {
        mlds[i] = msk[(size_t)(i >> 4) * TW + (i & 15)];
    }
    if (tid < TW) sup[tid] = 0ull;
    __syncthreads();
    if (tid >= 64) return;
    int lane = tid;
    int sel = 0;

    // ---- fast path: candidates [0, FN), all state in LDS ----
    {
        int p = 0;
        while (sel < NSEL) {
            int w0 = p >> 6;
            unsigned long long m = 0;
            if (lane < 16 && lane >= w0) {
                m = ~sup[lane];
                if (lane == w0) m &= (~0ull << (p & 63));
            }
            unsigned long long bal = __ballot(m != 0ull);
            if (bal == 0ull) break;
            int w = __builtin_ctzll(bal);
            int bit = __shfl(m ? __builtin_ctzll(m) : 0, w);
            int c = (w << 6) + bit;
            if (c >= FN) break;
            float4 cb = cboxes[c];
            float ca = careas[c];
            if (lane == 0) {
                unsigned long long key = sk2[c];
                out[sel * 4 + 0] = cb.x; out[sel * 4 + 1] = cb.y;
                out[sel * 4 + 2] = cb.z; out[sel * 4 + 3] = cb.w;
                out[1200 + sel] = __uint_as_float(0x3F800000u - (unsigned)(key >> 18));
                out[1500 + sel] = 1.f;
                sbox[sel] = cb;
                sarea[sel] = ca;
                sellist[sel] = (unsigned short)c;
            }
            sel++;
            if (lane < 16) sup[lane] |= mlds[c * 16 + lane];
            p = c + 1;
        }
    }

    // ---- slow path: candidates [FN, Tc) via global mask rows ----
    if (sel < NSEL && Tc > FN) {
        // lazily materialize tail sup words from already-selected rows
        unsigned long long acc = 0ull;
        if (lane >= 16) {
            for (int s = 0; s < sel; ++s)
                acc |= msk[(size_t)sellist[s] * TW + lane];
            sup[lane] = acc;
        }

        auto scanFrom = [&](int p) -> int {
            if (p < 0 || p >= Tc) return -1;
            int w = p >> 6;
            unsigned long long f = (~sup[w]) & (~0ull << (p & 63));
            while (f == 0ull) {
                ++w;
                if (w >= TW) return -1;
                f = ~sup[w];
            }
            int c = (w << 6) + __builtin_ctzll(f);
            return (c < Tc) ? c : -1;
        };

        unsigned long long r0 = 0, r1 = 0, r2n = 0;
        int idx = scanFrom(FN);
        if (idx >= 0) r0 = msk[(size_t)idx * TW + lane];
        int idx2 = (idx >= 0) ? scanFrom(idx + 1) : -1;
        if (idx2 >= 0) r1 = msk[(size_t)idx2 * TW + lane];

        while (idx >= 0 && sel < NSEL) {
            float4 cb = cboxes[idx];
            float ca = careas[idx];
            if (lane == 0) {
                unsigned long long key = sk2[idx];
                out[sel * 4 + 0] = cb.x; out[sel * 4 + 1] = cb.y;
                out[sel * 4 + 2] = cb.z; out[sel * 4 + 3] = cb.w;
                out[1200 + sel] = __uint_as_float(0x3F800000u - (unsigned)(key >> 18));
                out[1500 + sel] = 1.f;
                sbox[sel] = cb;
                sarea[sel] = ca;
            }
            sel++;
            if (sel >= NSEL) break;

            int idx3 = (idx2 >= 0) ? scanFrom(idx2 + 1) : -1;
            if (idx3 >= 0) r2n = msk[(size_t)idx3 * TW + lane];

            sup[lane] |= r0;

            if (idx2 >= 0) {
                unsigned long long w = sup[idx2 >> 6];
                if ((w >> (idx2 & 63)) & 1ull) {
                    idx2 = scanFrom(idx2);
                    if (idx2 >= 0) r1 = msk[(size_t)idx2 * TW + lane];
                    idx3 = (idx2 >= 0) ? scanFrom(idx2 + 1) : -1;
                    if (idx3 >= 0) r2n = msk[(size_t)idx3 * TW + lane];
                }
            }
            idx = idx2; r0 = r1;
            idx2 = idx3; r1 = r2n;
        }
    }

    // ---- exact tail beyond T_TOP ----
    if (sel < NSEL && total > T_TOP) {
        for (int i = T_TOP; i < total && sel < NSEL; ++i) {
            unsigned long long key = sk2[i];
            float4 cb = boxes[key & 0x3FFFFull];
            float ca = (cb.z - cb.x) * (cb.w - cb.y);
            int supp = 0;
            for (int t = lane; t < sel; t += 64) {
                float4 s4 = sbox[t];
                float iy = fmaxf(0.f, fminf(s4.z, cb.z) - fmaxf(s4.x, cb.x));
                float ix = fmaxf(0.f, fminf(s4.w, cb.w) - fmaxf(s4.y, cb.y));
                float inter = iy * ix;
                float iou = inter / (sarea[t] + ca - inter + 1e-9f);
                if (iou > 0.7f) supp = 1;
            }
            if (__ballot(supp) == 0ull) {
                if (lane == 0) {
                    out[sel * 4 + 0] = cb.x; out[sel * 4 + 1] = cb.y;
                    out[sel * 4 + 2] = cb.z; out[sel * 4 + 3] = cb.w;
                    out[1200 + sel] = __uint_as_float(0x3F800000u - (unsigned)(key >> 18));
                    out[1500 + sel] = 1.f;
                    sbox[sel] = cb;
                    sarea[sel] = ca;
                }
                sel++;
            }
        }
    }
}

extern "C" void kernel_launch(void* const* d_in, const int* in_sizes, int n_in,
                              void* d_out, int out_size, void* d_ws, size_t ws_size,
                              hipStream_t stream) {
    const float* feat = (const float*)d_in[0];
    const float* w1   = (const float*)d_in[1];
    const float* b1   = (const float*)d_in[2];
    const float* w2   = (const float*)d_in[3];
    const float* b2   = (const float*)d_in[4];
    const float* w_s  = (const float*)d_in[5];
    const float* b_s  = (const float*)d_in[6];
    const float* w_b  = (const float*)d_in[7];
    const float* b_b  = (const float*)d_in[8];
    float* out = (float*)d_out;
    char* ws = (char*)d_ws;

    if (ws_size >= NWS_TOTAL) {
        _Float16* a1h = (_Float16*)(ws + NWS_A1H);
        _Float16* a1l = (_Float16*)(ws + NWS_A1L);
        _Float16* w1h = (_Float16*)(ws + NWS_W1H);
        _Float16* w1l = (_Float16*)(ws + NWS_W1L);
        _Float16* a2h = (_Float16*)(ws + NWS_A2H);
        _Float16* a2l = (_Float16*)(ws + NWS_A2L);
        _Float16* w2h = (_Float16*)(ws + NWS_W2H);
        _Float16* w2l = (_Float16*)(ws + NWS_W2L);
        _Float16* xh  = (_Float16*)(ws + NWS_X2);
        _Float16* xl  = (_Float16*)(ws + NWS_X2 + 16777216);
        float4* boxes = (float4*)(ws + NWS_BOXES);
        unsigned long long* keys  = (unsigned long long*)(ws + NWS_KEYS);
        unsigned long long* skeys = (unsigned long long*)(ws + NWS_SKEYS);
        int* hist = (int*)(ws + NWS_HIST);
        int* cur  = (int*)(ws + NWS_CUR);
        int* cnt  = (int*)(ws + NWS_CNT);
        int* base = (int*)(ws + NWS_BASE);
        _Float16* wbh = (_Float16*)(ws + NWS_SKEYS);           // dead before scatter writes skeys
        _Float16* wbl = (_Float16*)(ws + NWS_SKEYS + 65536);
        unsigned long long* msk = (unsigned long long*)(ws + NWS_A1H);   // 2 MB
        float4* cbox  = (float4*)(ws + NWS_A1L);
        float*  carea = (float*)(ws + NWS_A1L + 262144);
        unsigned long long* sk2 = keys;

        hipMemsetAsync(ws + NWS_HIST, 0, (NWS_CNT - NWS_HIST) + 256, stream);
        convert_feat_kernel<<<dim3(130, 32), 256, 0, stream>>>(feat, a1h, a1l);
        prep_kernel<<<4100, 256, 0, stream>>>(w1, w1h, w1l, w2, w2h, w2l,
                                              w_s, w_b, wbh, wbl, a2h, a2l);
        conv_mfma_kernel<1024, true ><<<512, 256, 0, stream>>>(a1h, a1l, w1h, w1l, b1, a2h, a2l);
        conv_mfma_kernel< 512, false><<<512, 256, 0, stream>>>(a2h, a2l, w2h, w2l, b2, xh, xl);
        heads_mfma_kernel<<<128, 256, 0, stream>>>(xh, xl, wbh, wbl, b_s, b_b, boxes, keys, cnt, hist);
        scan_kernel<<<1, 256, 0, stream>>>(hist, base);
        scatter_kernel<<<576, 256, 0, stream>>>(keys, cnt, base, cur, skeys);
        sortb_kernel<<<NB, 256, 0, stream>>>(skeys, base, boxes, sk2, cbox, carea);
        mask_kernel<<<dim3(16, 16), 256, 0, stream>>>(cbox, carea, msk);
        walk_kernel<<<1, 256, 0, stream>>>(sk2, cnt, cbox, carea, msk, boxes, out);
    } else {
        float* x1 = (float*)(ws + WS_X1);
        float* x2 = (float*)(ws + WS_X2);
        float4* boxes = (float4*)(ws + WS_BOXES);
        unsigned long long* keys  = (unsigned long long*)(ws + WS_KEYS);
        unsigned long long* skeys = (unsigned long long*)(ws + WS_SKEYS);
        int* hist = (int*)(ws + WS_HIST);
        int* cur  = (int*)(ws + WS_CUR);
        int* cnt  = (int*)(ws + WS_CNT);
        int* base = (int*)(ws + WS_BASE);
        unsigned long long* msk = (unsigned long long*)(ws + WS_X1);
        float4* cbox  = (float4*)(ws + WS_X2);
        float*  carea = (float*)(ws + WS_X2 + 262144);
        unsigned long long* sk2 = keys;

        hipMemsetAsync(ws + WS_HIST, 0, (WS_CNT - WS_HIST) + 256, stream);
        conv3x3_kernel<1024, true,  true ><<<2048, 256, 0, stream>>>(feat, w1, b1, x1);
        conv3x3_kernel< 512, false, false><<<2048, 256, 0, stream>>>(x1,   w2, b2, x2);
        heads_decode_kernel<<<4096, 256, 0, stream>>>(x2, w_s, b_s, w_b, b_b, boxes, keys, cnt, hist);
        scan_kernel<<<1, 256, 0, stream>>>(hist, base);
        scatter_kernel<<<576, 256, 0, stream>>>(keys, cnt, base, cur, skeys);
        sortb_kernel<<<NB, 256, 0, stream>>>(skeys, base, boxes, sk2, cbox, carea);
        mask_kernel<<<dim3(16, 16), 256, 0, stream>>>(cbox, carea, msk);
        walk_kernel<<<1, 256, 0, stream>>>(sk2, cnt, cbox, carea, msk, boxes, out);
    }
}